// Round 11
// baseline (434.928 us; speedup 1.0000x reference)
//
#include <hip/hip_runtime.h>
#include <hip/hip_bf16.h>

#define B_ 16
#define C_ 256
#define N_ 4096

// log2(10000)/128
#define THK (13.287712379549449f / 128.f)

typedef float f4 __attribute__((ext_vector_type(4)));
typedef float f2 __attribute__((ext_vector_type(2)));
typedef short s8 __attribute__((ext_vector_type(8)));
typedef unsigned short us8 __attribute__((ext_vector_type(8)));
typedef unsigned int u4 __attribute__((ext_vector_type(4)));
typedef __fp16 hv2 __attribute__((ext_vector_type(2)));

__device__ __forceinline__ float bf2f(unsigned short u) {
    unsigned int ui = ((unsigned int)u) << 16;
    return __uint_as_float(ui);
}
__device__ __forceinline__ unsigned short f2bf(float f) {
    unsigned int ui = __float_as_uint(f);
    ui += 0x7fffu + ((ui >> 16) & 1u);
    return (unsigned short)(ui >> 16);
}

// packed f16 helpers (builtins use __fp16 vectors, NOT _Float16)
__device__ __forceinline__ unsigned int pk2h(float a, float b) {
#if __has_builtin(__builtin_amdgcn_cvt_pkrtz)
    union { hv2 h; unsigned int u; } x;
    x.h = __builtin_amdgcn_cvt_pkrtz(a, b);
    return x.u;
#else
    union { __fp16 h[2]; unsigned int u; } x;
    x.h[0] = (__fp16)a; x.h[1] = (__fp16)b; return x.u;
#endif
}
__device__ __forceinline__ float DOT2(unsigned int w, unsigned int xp, float c) {
    union { unsigned int u; hv2 h; } a, b; a.u = w; b.u = xp;
#if __has_builtin(__builtin_amdgcn_fdot2)
    return __builtin_amdgcn_fdot2(a.h, b.h, c, false);
#else
    return c + (float)a.h[0] * (float)b.h[0] + (float)a.h[1] * (float)b.h[1];
#endif
}

// ---------------------------------------------------------------------------
// K0: RoPE table  ropeT[w*128+jj] = (cos(w*theta_jj), sin(w*theta_jj))
// ---------------------------------------------------------------------------
__global__ __launch_bounds__(256) void k0_rope(float* __restrict__ ropeT)
{
    int idx = blockIdx.x * 256 + threadIdx.x;   // 8192
    int w = idx >> 7, jj = idx & 127;
    float theta = exp2f(-(float)jj * THK);
    float sv, cv; sincosf((float)w * theta, &sv, &cv);
    ropeT[idx * 2] = cv; ropeT[idx * 2 + 1] = sv;
}

// ---------------------------------------------------------------------------
// K1: 4 depthwise convs (k=3,5,7,9) via v_dot2_f32_f16 (best measured variant:
// 117us, VGPR 56). One block = one (b,c) 64x64 image; thread = 1 row x 16 cols.
// grid (256 c, 16 b), block 256. Tile: 72 rows x 88-pitch f16 (12.4 KB).
// ---------------------------------------------------------------------------
__global__ __launch_bounds__(256, 4) void k1_conv_stats(
    const float* __restrict__ x,
    const float* __restrict__ cw3, const float* __restrict__ cb3,
    const float* __restrict__ cw5, const float* __restrict__ cb5,
    const float* __restrict__ cw7, const float* __restrict__ cb7,
    const float* __restrict__ cw9, const float* __restrict__ cb9,
    unsigned short* __restrict__ y,   // [4][B][C][N] bf16
    float* __restrict__ stats)        // [4][B][4][2]
{
    __shared__ __align__(16) unsigned short tile[72 * 88];
    __shared__ __align__(16) unsigned int wtab[9][16];
    __shared__ float red[4][8];
    const int t = threadIdx.x;
    const int c  = blockIdx.x;
    const int b  = blockIdx.y;

    const float* xc = x + (size_t)(b * C_ + c) * N_;

    if (t < 144) {
        int r = t >> 4, slot = t & 15;
        float w0 = 0.f, w1 = 0.f;
        if (slot < 5) {
            int dx = slot * 2;
            w0 = cw9[c * 81 + r * 9 + dx];
            if (dx + 1 < 9) w1 = cw9[c * 81 + r * 9 + dx + 1];
        } else if (slot < 9) {
            int r7 = r - 1;
            if ((unsigned)r7 < 7u) {
                int dx = (slot - 5) * 2;
                w0 = cw7[c * 49 + r7 * 7 + dx];
                if (dx + 1 < 7) w1 = cw7[c * 49 + r7 * 7 + dx + 1];
            }
        } else if (slot < 12) {
            int r5 = r - 2;
            if ((unsigned)r5 < 5u) {
                int dx = (slot - 9) * 2;
                w0 = cw5[c * 25 + r5 * 5 + dx];
                if (dx + 1 < 5) w1 = cw5[c * 25 + r5 * 5 + dx + 1];
            }
        } else if (slot < 14) {
            int r3 = r - 3;
            if ((unsigned)r3 < 3u) {
                int dx = (slot - 12) * 2;
                w0 = cw3[c * 9 + r3 * 3 + dx];
                if (dx + 1 < 3) w1 = cw3[c * 9 + r3 * 3 + dx + 1];
            }
        }
        wtab[r][slot] = pk2h(w0, w1);
    }

    #pragma unroll 1
    for (int i = 0; i < 13; ++i) {
        int flat = i * 256 + t;              // pair index, 72*44 = 3168
        if (flat < 72 * 44) {
            int r = flat / 44, cp = flat % 44;
            int h = r - 4;
            int w0i = cp * 2 - 4, w1i = w0i + 1;
            float v0 = 0.f, v1 = 0.f;
            if ((unsigned)h < 64u) {
                const float* row = xc + h * 64;
                if ((unsigned)w0i < 64u) v0 = row[w0i];
                if ((unsigned)w1i < 64u) v1 = row[w1i];
            }
            *(unsigned int*)&tile[r * 88 + cp * 2] = pk2h(v0, v1);
        }
    }
    __syncthreads();

    const int w16 = (t & 3) * 16;   // column base: 0/16/32/48
    const int hr  = t >> 2;         // output row: 0..63
    float a3[16], a5[16], a7[16], a9[16];
    #pragma unroll
    for (int j = 0; j < 16; ++j) { a3[j]=0.f; a5[j]=0.f; a7[j]=0.f; a9[j]=0.f; }

    #pragma unroll 1
    for (int r9 = 0; r9 < 9; ++r9) {
        u4 wv0 = *(const u4*)&wtab[r9][0];
        u4 wv1 = *(const u4*)&wtab[r9][4];
        u4 wv2 = *(const u4*)&wtab[r9][8];
        u4 wv3 = *(const u4*)&wtab[r9][12];
        unsigned int wt[16] = { wv0[0],wv0[1],wv0[2],wv0[3],
                                wv1[0],wv1[1],wv1[2],wv1[3],
                                wv2[0],wv2[1],wv2[2],wv2[3],
                                wv3[0],wv3[1],wv3[2],wv3[3] };

        const unsigned short* xr = &tile[(hr + r9) * 88 + w16];
        u4 e0 = *(const u4*)(xr);
        u4 e1 = *(const u4*)(xr + 8);
        u4 e2 = *(const u4*)(xr + 16);
        unsigned int xe12 = *(const unsigned int*)(xr + 24);
        unsigned int xe[13] = { e0[0],e0[1],e0[2],e0[3],
                                e1[0],e1[1],e1[2],e1[3],
                                e2[0],e2[1],e2[2],e2[3], xe12 };
        unsigned int xo[12];
        #pragma unroll
        for (int k2 = 0; k2 < 12; ++k2)
            xo[k2] = (xe[k2] >> 16) | (xe[k2 + 1] << 16);

        #pragma unroll
        for (int j = 0; j < 16; ++j) {
            const int jh = j >> 1;
            if ((j & 1) == 0) {
                #pragma unroll
                for (int k = 0; k < 5; ++k) a9[j] = DOT2(wt[k], xe[jh + k], a9[j]);
            } else {
                #pragma unroll
                for (int k = 0; k < 5; ++k) a9[j] = DOT2(wt[k], xo[jh + k], a9[j]);
            }
        }
        if ((unsigned)(r9 - 1) < 7u) {
            #pragma unroll
            for (int j = 0; j < 16; ++j) {
                const int jh = j >> 1;
                if ((j & 1) == 0) {
                    #pragma unroll
                    for (int k = 0; k < 4; ++k) a7[j] = DOT2(wt[5 + k], xo[jh + k], a7[j]);
                } else {
                    #pragma unroll
                    for (int k = 0; k < 4; ++k) a7[j] = DOT2(wt[5 + k], xe[jh + 1 + k], a7[j]);
                }
            }
        }
        if ((unsigned)(r9 - 2) < 5u) {
            #pragma unroll
            for (int j = 0; j < 16; ++j) {
                const int jh = j >> 1;
                if ((j & 1) == 0) {
                    #pragma unroll
                    for (int k = 0; k < 3; ++k) a5[j] = DOT2(wt[9 + k], xe[jh + 1 + k], a5[j]);
                } else {
                    #pragma unroll
                    for (int k = 0; k < 3; ++k) a5[j] = DOT2(wt[9 + k], xo[jh + 1 + k], a5[j]);
                }
            }
        }
        if ((unsigned)(r9 - 3) < 3u) {
            #pragma unroll
            for (int j = 0; j < 16; ++j) {
                const int jh = j >> 1;
                if ((j & 1) == 0) {
                    #pragma unroll
                    for (int k = 0; k < 2; ++k) a3[j] = DOT2(wt[12 + k], xo[jh + 1 + k], a3[j]);
                } else {
                    #pragma unroll
                    for (int k = 0; k < 2; ++k) a3[j] = DOT2(wt[12 + k], xe[jh + 2 + k], a3[j]);
                }
            }
        }
    }

    float bb0 = cb3[c], bb1 = cb5[c], bb2 = cb7[c], bb3 = cb9[c];
    float s[4], ss[4];
    const size_t L = (size_t)B_ * C_ * N_;
    size_t ybase = (size_t)(b * C_ + c) * N_ + (size_t)hr * 64 + w16;

    #pragma unroll
    for (int l = 0; l < 4; ++l) {
        float bias = (l == 0) ? bb0 : (l == 1) ? bb1 : (l == 2) ? bb2 : bb3;
        float* ap = (l == 0) ? a3 : (l == 1) ? a5 : (l == 2) ? a7 : a9;
        float s1 = 0.f, s2 = 0.f;
        us8 pk0, pk1;
        #pragma unroll
        for (int j = 0; j < 8; ++j) {
            float v = ap[j] + bias;
            pk0[j] = f2bf(v);
            s1 += v; s2 += v * v;
        }
        #pragma unroll
        for (int j = 8; j < 16; ++j) {
            float v = ap[j] + bias;
            pk1[j - 8] = f2bf(v);
            s1 += v; s2 += v * v;
        }
        *reinterpret_cast<us8*>(y + (size_t)l * L + ybase)     = pk0;
        *reinterpret_cast<us8*>(y + (size_t)l * L + ybase + 8) = pk1;
        s[l] = s1; ss[l] = s2;
    }

    #pragma unroll
    for (int l = 0; l < 4; ++l) {
        float aa = s[l], qq = ss[l];
        for (int off = 1; off < 64; off <<= 1) { aa += __shfl_xor(aa, off); qq += __shfl_xor(qq, off); }
        s[l] = aa; ss[l] = qq;
    }
    const int lane = t & 63, wvi = t >> 6;
    if (lane == 0) {
        #pragma unroll
        for (int l = 0; l < 4; ++l) { red[wvi][l*2] = s[l]; red[wvi][l*2+1] = ss[l]; }
    }
    __syncthreads();
    if (t < 8) {
        float tot = red[0][t] + red[1][t] + red[2][t] + red[3][t];
        int l = t >> 1, which = t & 1, g = c >> 6;
        atomicAdd(&stats[((l * 16 + b) * 4 + g) * 2 + which], tot);
    }
}

// ---------------------------------------------------------------------------
// K2: groupnorm + sigmoid + softmax fusion; write vT bf16 [b,c,n] and
//     xs bf16 [b,n,c] (LDS transpose). Vectorized us8 loads/stores.
// grid (64 ntiles, 4 groups, 16 b), block 256
// ---------------------------------------------------------------------------
__global__ __launch_bounds__(256) void k2_fuse(
    const unsigned short* __restrict__ y, const float* __restrict__ stats,
    const float* __restrict__ gnw, const float* __restrict__ gnb,
    const float* __restrict__ fw,
    unsigned short* __restrict__ xs, unsigned short* __restrict__ vT)
{
    __shared__ float tile[64 * 65];
    const int t = threadIdx.x;
    const int n0 = blockIdx.x * 64;
    const int cg = blockIdx.y;
    const int b  = blockIdx.z;
    const int c0 = cg * 64;

    float f0 = fw[0], f1 = fw[1], f2 = fw[2], f3 = fw[3];
    float mx = fmaxf(fmaxf(f0, f1), fmaxf(f2, f3));
    float e0 = __expf(f0 - mx), e1 = __expf(f1 - mx), e2 = __expf(f2 - mx), e3 = __expf(f3 - mx);
    float inv = 1.f / (e0 + e1 + e2 + e3);
    float wts[4] = { e0 * inv, e1 * inv, e2 * inv, e3 * inv };

    float mean[4], rstd[4];
    const float invN = 1.0f / 262144.0f;
    #pragma unroll
    for (int l = 0; l < 4; ++l) {
        float s1 = stats[((l * 16 + b) * 4 + cg) * 2 + 0];
        float s2 = stats[((l * 16 + b) * 4 + cg) * 2 + 1];
        float m = s1 * invN;
        float var = fmaxf(s2 * invN - m * m, 0.f);
        mean[l] = m; rstd[l] = rsqrtf(var + 1e-5f);
    }

    const size_t L = (size_t)B_ * C_ * N_;
    const int ci = t >> 2;          // 0..63
    const int ns = (t & 3) * 16;    // 0/16/32/48
    const int c  = c0 + ci;
    const size_t base = (size_t)(b * C_ + c) * N_ + n0 + ns;

    float acc[16];
    #pragma unroll
    for (int j = 0; j < 16; ++j) acc[j] = 0.f;

    #pragma unroll
    for (int l = 0; l < 4; ++l) {
        float sc = rstd[l] * gnw[l * 256 + c];
        float of = gnb[l * 256 + c] - mean[l] * sc;
        float wt = wts[l];
        us8 v0 = *(const us8*)(y + (size_t)l * L + base);
        us8 v1 = *(const us8*)(y + (size_t)l * L + base + 8);
        #pragma unroll
        for (int j = 0; j < 8; ++j) {
            float g0 = fmaf(bf2f(v0[j]), sc, of);
            float g1 = fmaf(bf2f(v1[j]), sc, of);
            acc[j]     += wt * (1.0f / (1.0f + __expf(-g0)));
            acc[j + 8] += wt * (1.0f / (1.0f + __expf(-g1)));
        }
    }

    us8 p0, p1;
    #pragma unroll
    for (int j = 0; j < 8; ++j) { p0[j] = f2bf(acc[j]); p1[j] = f2bf(acc[j + 8]); }
    *(us8*)(vT + base)     = p0;
    *(us8*)(vT + base + 8) = p1;

    #pragma unroll
    for (int j = 0; j < 16; ++j) tile[ci * 65 + ns + j] = acc[j];
    __syncthreads();

    const int nj = t >> 2;
    const int cs = (t & 3) * 16;
    us8 q0, q1;
    #pragma unroll
    for (int j = 0; j < 8; ++j) {
        q0[j] = f2bf(tile[(cs + j) * 65 + nj]);
        q1[j] = f2bf(tile[(cs + 8 + j) * 65 + nj]);
    }
    unsigned short* xp = xs + ((size_t)b * N_ + n0 + nj) * C_ + c0 + cs;
    *(us8*)xp       = q0;
    *(us8*)(xp + 8) = q1;
}

__global__ __launch_bounds__(256) void k2b_cvt(const float* __restrict__ w,
                                              unsigned short* __restrict__ o, int n)
{
    int i = blockIdx.x * 256 + threadIdx.x;
    if (i < n) o[i] = f2bf(w[i]);
}

// ---------------------------------------------------------------------------
// K3: qk GEMM (bf16 MFMA). Block = 64 tokens x ALL 512 outputs (A staged in
//     LDS once). Waves 0,1 = q-half (RoPE in registers, table); waves 2,3 =
//     k-half (per-wave LDS transpose + RoPE + kmean). [R7-verified version]
// grid (1024), block 256
// ---------------------------------------------------------------------------
__global__ __launch_bounds__(256, 2) void k3_gemm(
    const short* __restrict__ A, const short* __restrict__ Bw,
    const float* __restrict__ ropeT,
    unsigned short* __restrict__ q_rope, unsigned short* __restrict__ k_ropeT,
    float* __restrict__ kmean)
{
    __shared__ short Atile[64 * 264];       // pitch 264 shorts (pad 8) = 33 KB
    __shared__ float kst[2][32 * 132];      // k-wave transpose stage, 33.8 KB
    const int t = threadIdx.x, lane = t & 63, wv = t >> 6;
    const int m0 = blockIdx.x * 64;         // global token base (b*4096 + tok)
    const int b = m0 >> 12;
    const int tokb = m0 & 4095;
    const int mr = lane & 15, koff = (lane >> 4) * 8, quad = lane >> 4;
    const int n0w = wv * 128;               // output channel base of this wave

    // stage A tile [64 tok][256 k] -> LDS (padded rows)
    {
        const short* src = A + (size_t)m0 * 256;
        #pragma unroll
        for (int i = 0; i < 8; ++i) {
            int flat = i * 2048 + t * 8;
            int row = flat >> 8, col = flat & 255;
            *(s8*)(Atile + row * 264 + col) = *(const s8*)(src + flat);
        }
    }
    __syncthreads();

    f4 acc[4][8];
    #pragma unroll
    for (int a = 0; a < 4; ++a)
        #pragma unroll
        for (int bn = 0; bn < 8; ++bn) { acc[a][bn][0]=0.f; acc[a][bn][1]=0.f; acc[a][bn][2]=0.f; acc[a][bn][3]=0.f; }

    #pragma unroll
    for (int ks = 0; ks < 8; ++ks) {
        const int k0 = ks * 32;
        s8 af[4], bfr[8];
        #pragma unroll
        for (int mt = 0; mt < 4; ++mt)
            af[mt] = *(const s8*)(Atile + (mt * 16 + mr) * 264 + k0 + koff);
        #pragma unroll
        for (int nt = 0; nt < 8; ++nt)
            bfr[nt] = *(const s8*)(Bw + (size_t)(n0w + nt * 16 + mr) * 256 + k0 + koff);
        #pragma unroll
        for (int mt = 0; mt < 4; ++mt)
            #pragma unroll
            for (int nt = 0; nt < 8; ++nt)
                acc[mt][nt] = __builtin_amdgcn_mfma_f32_16x16x32_bf16(af[mt], bfr[nt], acc[mt][nt], 0, 0, 0);
    }

    if (wv < 2) {
        // ---- q half: RoPE in registers, direct b16 stores ----
        #pragma unroll
        for (int mt = 0; mt < 4; ++mt) {
            #pragma unroll
            for (int r = 0; r < 4; ++r) {
                int tok = m0 + mt * 16 + quad * 4 + r;
                int w = tok & 63;
                unsigned short* orow = q_rope + (size_t)tok * 256;
                #pragma unroll
                for (int nt = 0; nt < 8; ++nt) {
                    int ch = n0w + nt * 16 + mr;
                    float v = acc[mt][nt][r];
                    v = v > 0.f ? v + 1.f : __expf(v);
                    float pv = __shfl_xor(v, 1);
                    int jj = ch >> 1;
                    f2 cs = *(const f2*)(ropeT + (w * 128 + jj) * 2);
                    float o = (ch & 1) ? cs[1] * pv + cs[0] * v : cs[0] * v - cs[1] * pv;
                    orow[ch] = f2bf(o);
                }
            }
        }
    } else {
        // ---- k half: per-wave LDS transpose + RoPE + kmean ----
        float* sw = kst[wv - 2];
        float ksum[2] = {0.f, 0.f};
        for (int half = 0; half < 2; ++half) {
            #pragma unroll
            for (int mt2 = 0; mt2 < 2; ++mt2) {
                int mt = half * 2 + mt2;
                #pragma unroll
                for (int nt = 0; nt < 8; ++nt)
                    #pragma unroll
                    for (int r = 0; r < 4; ++r) {
                        float v = acc[mt][nt][r];
                        v = v > 0.f ? v + 1.f : __expf(v);
                        sw[(mt2 * 16 + quad * 4 + r) * 132 + nt * 16 + mr] = v;
                    }
            }
            // same-wave RAW through LDS: ordered by waitcnt, no barrier needed
            #pragma unroll
            for (int cc = 0; cc < 2; ++cc) {
                int col = cc * 64 + lane;
                int kidx = (wv - 2) * 128 + col;      // 0..255
                int jj = kidx >> 1;
                unsigned short obuf[32];
                float ks = 0.f;
                #pragma unroll
                for (int i = 0; i < 32; ++i) {
                    float v = sw[i * 132 + col];
                    ks += v;
                    float pv = __shfl_xor(v, 1);
                    int w = (tokb + half * 32 + i) & 63;
                    f2 cs = *(const f2*)(ropeT + (w * 128 + jj) * 2);
                    obuf[i] = f2bf((kidx & 1) ? cs[1] * pv + cs[0] * v : cs[0] * v - cs[1] * pv);
                }
                unsigned short* dst = k_ropeT + (size_t)(b * 256 + kidx) * 4096 + tokb + half * 32;
                #pragma unroll
                for (int u = 0; u < 4; ++u)
                    *(us8*)(dst + u * 8) = *(const us8*)(obuf + u * 8);
                ksum[cc] += ks;
            }
        }
        atomicAdd(&kmean[b * 256 + (wv - 2) * 128 + lane], ksum[0] * (1.0f / 4096.0f));
        atomicAdd(&kmean[b * 256 + (wv - 2) * 128 + 64 + lane], ksum[1] * (1.0f / 4096.0f));
    }
}

// ---------------------------------------------------------------------------
// K5: kv[d,e] = (1/n) sum_n k_rope[n,d] v[n,e] via bf16 MFMA. Split-K = 4.
// grid (4 splits, 4 h, 16 b), block 256
// ---------------------------------------------------------------------------
__global__ __launch_bounds__(256) void k5_kv(
    const unsigned short* __restrict__ kT, const unsigned short* __restrict__ vT,
    float* __restrict__ kv)
{
    __shared__ float red[4 * 4096];
    const int t = threadIdx.x, lane = t & 63, wv = t >> 6;
    const int mr = lane & 15, koff = (lane >> 4) * 8, quad = lane >> 4;
    const int s = blockIdx.x, h = blockIdx.y, b = blockIdx.z;

    f4 acc[4][4];
    #pragma unroll
    for (int a = 0; a < 4; ++a)
        #pragma unroll
        for (int bn = 0; bn < 4; ++bn) { acc[a][bn][0]=0.f; acc[a][bn][1]=0.f; acc[a][bn][2]=0.f; acc[a][bn][3]=0.f; }

    #pragma unroll 1
    for (int it = 0; it < 4; ++it) {
        const int tok0 = s * 1024 + it * 256 + wv * 64;
        const unsigned short* Ab = kT + (size_t)(b * 256 + h * 64) * 4096 + tok0;
        const unsigned short* Bb = vT + (size_t)(b * 256 + h * 64) * 4096 + tok0;
        #pragma unroll
        for (int ks = 0; ks < 2; ++ks) {
            s8 af[4], bfr[4];
            #pragma unroll
            for (int mt = 0; mt < 4; ++mt)
                af[mt] = *(const s8*)(Ab + (size_t)(mt * 16 + mr) * 4096 + ks * 32 + koff);
            #pragma unroll
            for (int nt = 0; nt < 4; ++nt)
                bfr[nt] = *(const s8*)(Bb + (size_t)(nt * 16 + mr) * 4096 + ks * 32 + koff);
            #pragma unroll
            for (int mt = 0; mt < 4; ++mt)
                #pragma unroll
                for (int nt = 0; nt < 4; ++nt)
                    acc[mt][nt] = __builtin_amdgcn_mfma_f32_16x16x32_bf16(af[mt], bfr[nt], acc[mt][nt], 0, 0, 0);
        }
    }

    float* rw = red + wv * 4096;
    #pragma unroll
    for (int mt = 0; mt < 4; ++mt)
        #pragma unroll
        for (int nt = 0; nt < 4; ++nt)
            #pragma unroll
            for (int r = 0; r < 4; ++r)
                rw[(mt * 16 + quad * 4 + r) * 64 + nt * 16 + mr] = acc[mt][nt][r];
    __syncthreads();

    float* kvp = kv + (size_t)(b * 4 + h) * 4096;
    for (int i = 0; i < 16; ++i) {
        int idx = i * 256 + t;
        float s4 = red[idx] + red[4096 + idx] + red[8192 + idx] + red[12288 + idx];
        atomicAdd(&kvp[idx], s4 * (1.0f / 4096.0f));
    }
}

// ---------------------------------------------------------------------------
// K6: attn = (q_rope @ kv) * z via bf16 MFMA + FUSED LePE, single write.
// NEW: the LePE vT taps are staged in LDS via coalesced loads. The old code
// gathered per-lane-channel rows straight from global (lane stride 8 KB):
// ~36 VMEM loads x 64 cache lines each per thread = ~1.2 GB of L2/L3 line
// traffic per dispatch. Staging: 6 rows x 64 ch x 64 cols = 48 KB, 12
// coalesced us8 loads/thread, LDS pitch 70 shorts (bank = 3*lane mod 32,
// conflict-free reads; b32 staging writes since 140 B rows break 16B align).
// trans buffer is bf16 (pitch 65) and kml removed (uniform global reads) to
// fit 2 blocks/CU: LDS = 8K kvB + 1K zl + 52.5K vs + 16.25K trans = 77.8 KB.
// grid (16 ntiles, 4 h, 16 b), block 256
// ---------------------------------------------------------------------------
__global__ __launch_bounds__(256) void k6_attn(
    const unsigned short* __restrict__ q_rope, const float* __restrict__ kmean,
    const float* __restrict__ kv, const float* __restrict__ ropeT,
    const unsigned short* __restrict__ vT, const float* __restrict__ lw,
    const float* __restrict__ lb, float* __restrict__ out)
{
    __shared__ __align__(16) unsigned short kvB[64 * 64];       // 8 KB
    __shared__ float zl[256];                                   // 1 KB
    __shared__ __align__(16) unsigned short vs[6 * 64 * 70];    // 52.5 KB
    __shared__ __align__(16) unsigned short transb[4][32 * 65]; // 16.25 KB
    const int t = threadIdx.x, lane = t & 63, wv = t >> 6;
    const int mr = lane & 15, koff = (lane >> 4) * 8, quad = lane >> 4;
    const int ntb = blockIdx.x, h = blockIdx.y, b = blockIdx.z;
    const int n0 = ntb * 256;

    // --- stage kv tile (transposed, bf16) ---
    {
        const float* kvp = kv + (size_t)(b * 4 + h) * 4096;
        int e = t >> 2, dseg = (t & 3) * 16;
        unsigned short tmp[16];
        #pragma unroll
        for (int i = 0; i < 16; ++i) tmp[i] = f2bf(kvp[(dseg + i) * 64 + e]);
        *(us8*)&kvB[e * 64 + dseg]     = *(const us8*)tmp;
        *(us8*)&kvB[e * 64 + dseg + 8] = *(const us8*)(tmp + 8);
    }

    // --- stage vT rows [4*ntb-1 .. 4*ntb+4] x 64 ch into vs (coalesced) ---
    {
        const unsigned short* vbase = vT + (size_t)(b * 256 + h * 64) * 4096;
        const int r0 = 4 * ntb - 1;
        #pragma unroll
        for (int i = 0; i < 12; ++i) {
            int flat = i * 256 + t;          // 0..3071 = 64ch x 6rows x 8chunks
            int ch = flat / 48;
            int rc = flat % 48;
            int row = rc >> 3, chunk = rc & 7;
            int rr = r0 + row;
            union { us8 s; unsigned int u[4]; } v;
            if ((unsigned)rr < 64u)
                v.s = *(const us8*)(vbase + (size_t)ch * 4096 + rr * 64 + chunk * 8);
            else
                v.u[0] = v.u[1] = v.u[2] = v.u[3] = 0u;
            unsigned short* dst = vs + (row * 64 + ch) * 70 + chunk * 8;
            *(unsigned int*)(dst)     = v.u[0];
            *(unsigned int*)(dst + 2) = v.u[1];
            *(unsigned int*)(dst + 4) = v.u[2];
            *(unsigned int*)(dst + 6) = v.u[3];
        }
    }
    __syncthreads();

    // --- z denominators (kmean read directly from global; uniform addrs) ---
    {
        const unsigned short* qp = q_rope + (size_t)(b * 4096 + n0 + t) * 256 + h * 64;
        const float* kmp = kmean + b * 256 + h * 64;
        float q[64];
        #pragma unroll
        for (int u = 0; u < 8; ++u) {
            us8 v = *(const us8*)(qp + u * 8);
            #pragma unroll
            for (int j = 0; j < 8; ++j) q[u * 8 + j] = bf2f(v[j]);
        }
        int w = (n0 + t) & 63;
        float den = 0.f;
        #pragma unroll
        for (int j = 0; j < 32; ++j) {
            f2 cs = *(const f2*)(ropeT + (w * 128 + h * 32 + j) * 2);
            float kmx = kmp[2 * j], kmy = kmp[2 * j + 1];
            den += q[2 * j] * (cs[0] * kmx - cs[1] * kmy) + q[2 * j + 1] * (cs[1] * kmx + cs[0] * kmy);
        }
        zl[t] = 1.0f / (den + 1e-6f);
    }
    __syncthreads();

    s8 bfr[4][2];
    #pragma unroll
    for (int nt = 0; nt < 4; ++nt)
        #pragma unroll
        for (int ks = 0; ks < 2; ++ks)
            bfr[nt][ks] = *(const s8*)&kvB[(nt * 16 + mr) * 64 + ks * 32 + koff];

    const unsigned short* Ab = q_rope + (size_t)(b * 4096 + n0 + wv * 64) * 256 + h * 64;
    f4 acc[4][4];
    #pragma unroll
    for (int a = 0; a < 4; ++a)
        #pragma unroll
        for (int bn = 0; bn < 4; ++bn) { acc[a][bn][0]=0.f; acc[a][bn][1]=0.f; acc[a][bn][2]=0.f; acc[a][bn][3]=0.f; }

    #pragma unroll
    for (int ks = 0; ks < 2; ++ks) {
        s8 af[4];
        #pragma unroll
        for (int mt = 0; mt < 4; ++mt)
            af[mt] = *(const s8*)(Ab + (size_t)(mt * 16 + mr) * 256 + ks * 32 + koff);
        #pragma unroll
        for (int mt = 0; mt < 4; ++mt)
            #pragma unroll
            for (int nt = 0; nt < 4; ++nt)
                acc[mt][nt] = __builtin_amdgcn_mfma_f32_16x16x32_bf16(af[mt], bfr[nt][ks], acc[mt][nt], 0, 0, 0);
    }

    // LePE weights for this thread's channel c = h*64 + lane
    const int c = h * 64 + lane;
    f4 lwa = *(const f4*)(lw + c * 9);
    f4 lwb = *(const f4*)(lw + c * 9 + 4);
    float lw8 = lw[c * 9 + 8];
    float bias = lb[c];

    unsigned short* sw = transb[wv];
    const int rimg = 4 * ntb + wv;              // wave-uniform output row
    #pragma unroll
    for (int half = 0; half < 2; ++half) {
        #pragma unroll
        for (int mt2 = 0; mt2 < 2; ++mt2) {
            #pragma unroll
            for (int r = 0; r < 4; ++r) {
                int row_rel = mt2 * 16 + quad * 4 + r;
                float z = zl[wv * 64 + half * 32 + row_rel];
                #pragma unroll
                for (int nt = 0; nt < 4; ++nt)
                    sw[row_rel * 65 + nt * 16 + mr] = f2bf(acc[half * 2 + mt2][nt][r] * z);
            }
        }
        __syncthreads();
        float tmp[32];
        #pragma unroll
        for (int i = 0; i < 32; ++i) tmp[i] = bf2f(sw[i * 65 + lane]) + bias;

        // --- fused LePE from LDS: taps vs[row][ch=lane][col], pitch 70 ---
        const int CST = half * 32;              // compile-time (half unrolled)
        #pragma unroll
        for (int dy = -1; dy <= 1; ++dy) {
            int rr = rimg + dy;
            if ((unsigned)rr < 64u) {           // wave-uniform branch
                int lr = wv + dy + 1;           // 0..5
                const unsigned short* vrow = vs + (lr * 64 + lane) * 70;
                float f[34];
                #pragma unroll
                for (int i = 0; i < 34; ++i) {
                    int col = CST - 1 + i;
                    f[i] = ((unsigned)col < 64u) ? bf2f(vrow[col]) : 0.f;
                }
                float w0, w1, w2;
                if (dy == -1)      { w0 = lwa[0]; w1 = lwa[1]; w2 = lwa[2]; }
                else if (dy == 0)  { w0 = lwa[3]; w1 = lwb[0]; w2 = lwb[1]; }
                else               { w0 = lwb[2]; w1 = lwb[3]; w2 = lw8;    }
                #pragma unroll
                for (int j = 0; j < 32; ++j) {
                    float o = tmp[j];
                    o = fmaf(w0, f[j], o);
                    o = fmaf(w1, f[j + 1], o);
                    o = fmaf(w2, f[j + 2], o);
                    tmp[j] = o;
                }
            }
        }

        float* orow = out + (size_t)(b * 256 + c) * 4096 + n0 + wv * 64 + half * 32;
        #pragma unroll
        for (int u = 0; u < 8; ++u)
            *(f4*)(orow + u * 4) = *(const f4*)(tmp + u * 4);
        __syncthreads();
    }
}

// ---------------------------------------------------------------------------
extern "C" void kernel_launch(void* const* d_in, const int* in_sizes, int n_in,
                              void* d_out, int out_size, void* d_ws, size_t ws_size,
                              hipStream_t stream)
{
    const float* x   = (const float*)d_in[0];
    const float* w3  = (const float*)d_in[1];  const float* b3 = (const float*)d_in[2];
    const float* w5  = (const float*)d_in[3];  const float* b5 = (const float*)d_in[4];
    const float* w7  = (const float*)d_in[5];  const float* b7 = (const float*)d_in[6];
    const float* w9  = (const float*)d_in[7];  const float* b9 = (const float*)d_in[8];
    const float* gnw = (const float*)d_in[9];  const float* gnb = (const float*)d_in[10];
    const float* fw  = (const float*)d_in[11];
    const float* qkw = (const float*)d_in[12];
    const float* lw  = (const float*)d_in[13]; const float* lb = (const float*)d_in[14];

    char* ws = (char*)d_ws;
    // layout (bytes):
    //   [0, 128MiB)     y bf16 [4][B][C][N]  -- ALIASED later by q_rope (0..32M)
    //                   and k_ropeT (32M..64M); y dead after k2.
    //   [128M, 160M)    xs bf16 [B][N][C]
    //   [160M, 192M)    vT bf16 [B][C][N]
    //   [192M, +256K)   qk_w bf16
    //   then stats (2KB) | kmean (16KB) | kv fp32 (1MB)  -- one memset
    //   then ropeT fp32 64KB (fully overwritten by k0, no memset)
    unsigned short* y      = (unsigned short*)(ws + 0);
    unsigned short* q_rope = (unsigned short*)(ws + 0);
    unsigned short* kT     = (unsigned short*)(ws + 33554432ull);
    unsigned short* xs     = (unsigned short*)(ws + 134217728ull);
    unsigned short* vT     = (unsigned short*)(ws + 167772160ull);
    unsigned short* wb     = (unsigned short*)(ws + 201326592ull);
    float*          stats  = (float*)(ws + 201588736ull);
    float*          kmean  = (float*)(ws + 201590784ull);
    float*          kv     = (float*)(ws + 201607168ull);
    float*          ropeT  = (float*)(ws + 202655744ull);

    (void)hipMemsetAsync(stats, 0, 2048 + 16384 + 1048576, stream);

    k0_rope<<<dim3(32), 256, 0, stream>>>(ropeT);
    k1_conv_stats<<<dim3(256, 16), 256, 0, stream>>>(x, w3, b3, w5, b5, w7, b7, w9, b9, y, stats);
    k2b_cvt<<<dim3(512), 256, 0, stream>>>(qkw, wb, 131072);
    k2_fuse<<<dim3(64, 4, 16), 256, 0, stream>>>(y, stats, gnw, gnb, fw, xs, vT);
    k3_gemm<<<dim3(1024), 256, 0, stream>>>((const short*)xs, (const short*)wb, ropeT, q_rope, kT, kmean);
    k5_kv<<<dim3(4, 4, 16), 256, 0, stream>>>(kT, vT, kv);
    k6_attn<<<dim3(16, 4, 16), 256, 0, stream>>>(q_rope, kmean, kv, ropeT, vT, lw, lb, (float*)d_out);
}

// Round 12
// 402.536 us; speedup vs baseline: 1.0805x; 1.0805x over previous
//
#include <hip/hip_runtime.h>
#include <hip/hip_bf16.h>

#define B_ 16
#define C_ 256
#define N_ 4096

// log2(10000)/128
#define THK (13.287712379549449f / 128.f)

typedef float f4 __attribute__((ext_vector_type(4)));
typedef float f2 __attribute__((ext_vector_type(2)));
typedef short s8 __attribute__((ext_vector_type(8)));
typedef unsigned short us8 __attribute__((ext_vector_type(8)));
typedef unsigned int u4 __attribute__((ext_vector_type(4)));
typedef __fp16 hv2 __attribute__((ext_vector_type(2)));

__device__ __forceinline__ float bf2f(unsigned short u) {
    unsigned int ui = ((unsigned int)u) << 16;
    return __uint_as_float(ui);
}
__device__ __forceinline__ unsigned short f2bf(float f) {
    unsigned int ui = __float_as_uint(f);
    ui += 0x7fffu + ((ui >> 16) & 1u);
    return (unsigned short)(ui >> 16);
}

// packed f16 helpers (builtins use __fp16 vectors, NOT _Float16)
__device__ __forceinline__ unsigned int pk2h(float a, float b) {
#if __has_builtin(__builtin_amdgcn_cvt_pkrtz)
    union { hv2 h; unsigned int u; } x;
    x.h = __builtin_amdgcn_cvt_pkrtz(a, b);
    return x.u;
#else
    union { __fp16 h[2]; unsigned int u; } x;
    x.h[0] = (__fp16)a; x.h[1] = (__fp16)b; return x.u;
#endif
}
__device__ __forceinline__ float DOT2(unsigned int w, unsigned int xp, float c) {
    union { unsigned int u; hv2 h; } a, b; a.u = w; b.u = xp;
#if __has_builtin(__builtin_amdgcn_fdot2)
    return __builtin_amdgcn_fdot2(a.h, b.h, c, false);
#else
    return c + (float)a.h[0] * (float)b.h[0] + (float)a.h[1] * (float)b.h[1];
#endif
}

// ---------------------------------------------------------------------------
// K0: setup — RoPE table (first 8192 threads) + qkw f32->bf16 cvt (all
// 131072 threads). Merges the old k0 + k2b launches.
// grid (512), block 256
// ---------------------------------------------------------------------------
__global__ __launch_bounds__(256) void k0_setup(float* __restrict__ ropeT,
                                                const float* __restrict__ w,
                                                unsigned short* __restrict__ o)
{
    int i = blockIdx.x * 256 + threadIdx.x;     // 0..131071
    o[i] = f2bf(w[i]);
    if (i < 8192) {
        int wr = i >> 7, jj = i & 127;
        float theta = exp2f(-(float)jj * THK);
        float sv, cv; sincosf((float)wr * theta, &sv, &cv);
        ropeT[i * 2] = cv; ropeT[i * 2 + 1] = sv;
    }
}

// ---------------------------------------------------------------------------
// K1: 4 depthwise convs (k=3,5,7,9) via v_dot2_f32_f16 (best measured variant:
// 117us, VGPR 56). One block = one (b,c) 64x64 image; thread = 1 row x 16 cols.
// grid (256 c, 16 b), block 256. Tile: 72 rows x 88-pitch f16 (12.4 KB).
// ---------------------------------------------------------------------------
__global__ __launch_bounds__(256, 4) void k1_conv_stats(
    const float* __restrict__ x,
    const float* __restrict__ cw3, const float* __restrict__ cb3,
    const float* __restrict__ cw5, const float* __restrict__ cb5,
    const float* __restrict__ cw7, const float* __restrict__ cb7,
    const float* __restrict__ cw9, const float* __restrict__ cb9,
    unsigned short* __restrict__ y,   // [4][B][C][N] bf16
    float* __restrict__ stats)        // [4][B][4][2]
{
    __shared__ __align__(16) unsigned short tile[72 * 88];
    __shared__ __align__(16) unsigned int wtab[9][16];
    __shared__ float red[4][8];
    const int t = threadIdx.x;
    const int c  = blockIdx.x;
    const int b  = blockIdx.y;

    const float* xc = x + (size_t)(b * C_ + c) * N_;

    if (t < 144) {
        int r = t >> 4, slot = t & 15;
        float w0 = 0.f, w1 = 0.f;
        if (slot < 5) {
            int dx = slot * 2;
            w0 = cw9[c * 81 + r * 9 + dx];
            if (dx + 1 < 9) w1 = cw9[c * 81 + r * 9 + dx + 1];
        } else if (slot < 9) {
            int r7 = r - 1;
            if ((unsigned)r7 < 7u) {
                int dx = (slot - 5) * 2;
                w0 = cw7[c * 49 + r7 * 7 + dx];
                if (dx + 1 < 7) w1 = cw7[c * 49 + r7 * 7 + dx + 1];
            }
        } else if (slot < 12) {
            int r5 = r - 2;
            if ((unsigned)r5 < 5u) {
                int dx = (slot - 9) * 2;
                w0 = cw5[c * 25 + r5 * 5 + dx];
                if (dx + 1 < 5) w1 = cw5[c * 25 + r5 * 5 + dx + 1];
            }
        } else if (slot < 14) {
            int r3 = r - 3;
            if ((unsigned)r3 < 3u) {
                int dx = (slot - 12) * 2;
                w0 = cw3[c * 9 + r3 * 3 + dx];
                if (dx + 1 < 3) w1 = cw3[c * 9 + r3 * 3 + dx + 1];
            }
        }
        wtab[r][slot] = pk2h(w0, w1);
    }

    #pragma unroll 1
    for (int i = 0; i < 13; ++i) {
        int flat = i * 256 + t;              // pair index, 72*44 = 3168
        if (flat < 72 * 44) {
            int r = flat / 44, cp = flat % 44;
            int h = r - 4;
            int w0i = cp * 2 - 4, w1i = w0i + 1;
            float v0 = 0.f, v1 = 0.f;
            if ((unsigned)h < 64u) {
                const float* row = xc + h * 64;
                if ((unsigned)w0i < 64u) v0 = row[w0i];
                if ((unsigned)w1i < 64u) v1 = row[w1i];
            }
            *(unsigned int*)&tile[r * 88 + cp * 2] = pk2h(v0, v1);
        }
    }
    __syncthreads();

    const int w16 = (t & 3) * 16;   // column base: 0/16/32/48
    const int hr  = t >> 2;         // output row: 0..63
    float a3[16], a5[16], a7[16], a9[16];
    #pragma unroll
    for (int j = 0; j < 16; ++j) { a3[j]=0.f; a5[j]=0.f; a7[j]=0.f; a9[j]=0.f; }

    #pragma unroll 1
    for (int r9 = 0; r9 < 9; ++r9) {
        u4 wv0 = *(const u4*)&wtab[r9][0];
        u4 wv1 = *(const u4*)&wtab[r9][4];
        u4 wv2 = *(const u4*)&wtab[r9][8];
        u4 wv3 = *(const u4*)&wtab[r9][12];
        unsigned int wt[16] = { wv0[0],wv0[1],wv0[2],wv0[3],
                                wv1[0],wv1[1],wv1[2],wv1[3],
                                wv2[0],wv2[1],wv2[2],wv2[3],
                                wv3[0],wv3[1],wv3[2],wv3[3] };

        const unsigned short* xr = &tile[(hr + r9) * 88 + w16];
        u4 e0 = *(const u4*)(xr);
        u4 e1 = *(const u4*)(xr + 8);
        u4 e2 = *(const u4*)(xr + 16);
        unsigned int xe12 = *(const unsigned int*)(xr + 24);
        unsigned int xe[13] = { e0[0],e0[1],e0[2],e0[3],
                                e1[0],e1[1],e1[2],e1[3],
                                e2[0],e2[1],e2[2],e2[3], xe12 };
        unsigned int xo[12];
        #pragma unroll
        for (int k2 = 0; k2 < 12; ++k2)
            xo[k2] = (xe[k2] >> 16) | (xe[k2 + 1] << 16);

        #pragma unroll
        for (int j = 0; j < 16; ++j) {
            const int jh = j >> 1;
            if ((j & 1) == 0) {
                #pragma unroll
                for (int k = 0; k < 5; ++k) a9[j] = DOT2(wt[k], xe[jh + k], a9[j]);
            } else {
                #pragma unroll
                for (int k = 0; k < 5; ++k) a9[j] = DOT2(wt[k], xo[jh + k], a9[j]);
            }
        }
        if ((unsigned)(r9 - 1) < 7u) {
            #pragma unroll
            for (int j = 0; j < 16; ++j) {
                const int jh = j >> 1;
                if ((j & 1) == 0) {
                    #pragma unroll
                    for (int k = 0; k < 4; ++k) a7[j] = DOT2(wt[5 + k], xo[jh + k], a7[j]);
                } else {
                    #pragma unroll
                    for (int k = 0; k < 4; ++k) a7[j] = DOT2(wt[5 + k], xe[jh + 1 + k], a7[j]);
                }
            }
        }
        if ((unsigned)(r9 - 2) < 5u) {
            #pragma unroll
            for (int j = 0; j < 16; ++j) {
                const int jh = j >> 1;
                if ((j & 1) == 0) {
                    #pragma unroll
                    for (int k = 0; k < 3; ++k) a5[j] = DOT2(wt[9 + k], xe[jh + 1 + k], a5[j]);
                } else {
                    #pragma unroll
                    for (int k = 0; k < 3; ++k) a5[j] = DOT2(wt[9 + k], xo[jh + 1 + k], a5[j]);
                }
            }
        }
        if ((unsigned)(r9 - 3) < 3u) {
            #pragma unroll
            for (int j = 0; j < 16; ++j) {
                const int jh = j >> 1;
                if ((j & 1) == 0) {
                    #pragma unroll
                    for (int k = 0; k < 2; ++k) a3[j] = DOT2(wt[12 + k], xo[jh + 1 + k], a3[j]);
                } else {
                    #pragma unroll
                    for (int k = 0; k < 2; ++k) a3[j] = DOT2(wt[12 + k], xe[jh + 2 + k], a3[j]);
                }
            }
        }
    }

    float bb0 = cb3[c], bb1 = cb5[c], bb2 = cb7[c], bb3 = cb9[c];
    float s[4], ss[4];
    const size_t L = (size_t)B_ * C_ * N_;
    size_t ybase = (size_t)(b * C_ + c) * N_ + (size_t)hr * 64 + w16;

    #pragma unroll
    for (int l = 0; l < 4; ++l) {
        float bias = (l == 0) ? bb0 : (l == 1) ? bb1 : (l == 2) ? bb2 : bb3;
        float* ap = (l == 0) ? a3 : (l == 1) ? a5 : (l == 2) ? a7 : a9;
        float s1 = 0.f, s2 = 0.f;
        us8 pk0, pk1;
        #pragma unroll
        for (int j = 0; j < 8; ++j) {
            float v = ap[j] + bias;
            pk0[j] = f2bf(v);
            s1 += v; s2 += v * v;
        }
        #pragma unroll
        for (int j = 8; j < 16; ++j) {
            float v = ap[j] + bias;
            pk1[j - 8] = f2bf(v);
            s1 += v; s2 += v * v;
        }
        *reinterpret_cast<us8*>(y + (size_t)l * L + ybase)     = pk0;
        *reinterpret_cast<us8*>(y + (size_t)l * L + ybase + 8) = pk1;
        s[l] = s1; ss[l] = s2;
    }

    #pragma unroll
    for (int l = 0; l < 4; ++l) {
        float aa = s[l], qq = ss[l];
        for (int off = 1; off < 64; off <<= 1) { aa += __shfl_xor(aa, off); qq += __shfl_xor(qq, off); }
        s[l] = aa; ss[l] = qq;
    }
    const int lane = t & 63, wvi = t >> 6;
    if (lane == 0) {
        #pragma unroll
        for (int l = 0; l < 4; ++l) { red[wvi][l*2] = s[l]; red[wvi][l*2+1] = ss[l]; }
    }
    __syncthreads();
    if (t < 8) {
        float tot = red[0][t] + red[1][t] + red[2][t] + red[3][t];
        int l = t >> 1, which = t & 1, g = c >> 6;
        atomicAdd(&stats[((l * 16 + b) * 4 + g) * 2 + which], tot);
    }
}

// ---------------------------------------------------------------------------
// K2: groupnorm + sigmoid + softmax fusion; write vT bf16 [b,c,n] and
//     xs bf16 [b,n,c] (LDS transpose). Vectorized us8 loads/stores.
// grid (64 ntiles, 4 groups, 16 b), block 256
// ---------------------------------------------------------------------------
__global__ __launch_bounds__(256) void k2_fuse(
    const unsigned short* __restrict__ y, const float* __restrict__ stats,
    const float* __restrict__ gnw, const float* __restrict__ gnb,
    const float* __restrict__ fw,
    unsigned short* __restrict__ xs, unsigned short* __restrict__ vT)
{
    __shared__ float tile[64 * 65];
    const int t = threadIdx.x;
    const int n0 = blockIdx.x * 64;
    const int cg = blockIdx.y;
    const int b  = blockIdx.z;
    const int c0 = cg * 64;

    float f0 = fw[0], f1 = fw[1], f2 = fw[2], f3 = fw[3];
    float mx = fmaxf(fmaxf(f0, f1), fmaxf(f2, f3));
    float e0 = __expf(f0 - mx), e1 = __expf(f1 - mx), e2 = __expf(f2 - mx), e3 = __expf(f3 - mx);
    float inv = 1.f / (e0 + e1 + e2 + e3);
    float wts[4] = { e0 * inv, e1 * inv, e2 * inv, e3 * inv };

    float mean[4], rstd[4];
    const float invN = 1.0f / 262144.0f;
    #pragma unroll
    for (int l = 0; l < 4; ++l) {
        float s1 = stats[((l * 16 + b) * 4 + cg) * 2 + 0];
        float s2 = stats[((l * 16 + b) * 4 + cg) * 2 + 1];
        float m = s1 * invN;
        float var = fmaxf(s2 * invN - m * m, 0.f);
        mean[l] = m; rstd[l] = rsqrtf(var + 1e-5f);
    }

    const size_t L = (size_t)B_ * C_ * N_;
    const int ci = t >> 2;          // 0..63
    const int ns = (t & 3) * 16;    // 0/16/32/48
    const int c  = c0 + ci;
    const size_t base = (size_t)(b * C_ + c) * N_ + n0 + ns;

    float acc[16];
    #pragma unroll
    for (int j = 0; j < 16; ++j) acc[j] = 0.f;

    #pragma unroll
    for (int l = 0; l < 4; ++l) {
        float sc = rstd[l] * gnw[l * 256 + c];
        float of = gnb[l * 256 + c] - mean[l] * sc;
        float wt = wts[l];
        us8 v0 = *(const us8*)(y + (size_t)l * L + base);
        us8 v1 = *(const us8*)(y + (size_t)l * L + base + 8);
        #pragma unroll
        for (int j = 0; j < 8; ++j) {
            float g0 = fmaf(bf2f(v0[j]), sc, of);
            float g1 = fmaf(bf2f(v1[j]), sc, of);
            acc[j]     += wt * (1.0f / (1.0f + __expf(-g0)));
            acc[j + 8] += wt * (1.0f / (1.0f + __expf(-g1)));
        }
    }

    us8 p0, p1;
    #pragma unroll
    for (int j = 0; j < 8; ++j) { p0[j] = f2bf(acc[j]); p1[j] = f2bf(acc[j + 8]); }
    *(us8*)(vT + base)     = p0;
    *(us8*)(vT + base + 8) = p1;

    #pragma unroll
    for (int j = 0; j < 16; ++j) tile[ci * 65 + ns + j] = acc[j];
    __syncthreads();

    const int nj = t >> 2;
    const int cs = (t & 3) * 16;
    us8 q0, q1;
    #pragma unroll
    for (int j = 0; j < 8; ++j) {
        q0[j] = f2bf(tile[(cs + j) * 65 + nj]);
        q1[j] = f2bf(tile[(cs + 8 + j) * 65 + nj]);
    }
    unsigned short* xp = xs + ((size_t)b * N_ + n0 + nj) * C_ + c0 + cs;
    *(us8*)xp       = q0;
    *(us8*)(xp + 8) = q1;
}

// ---------------------------------------------------------------------------
// K3: qk GEMM (bf16 MFMA). Block = 64 tokens x ALL 512 outputs (A staged in
//     LDS once). Waves 0,1 = q-half (RoPE in registers, table); waves 2,3 =
//     k-half (per-wave LDS transpose + RoPE + kmean). [R7-verified version]
// grid (1024), block 256
// ---------------------------------------------------------------------------
__global__ __launch_bounds__(256, 2) void k3_gemm(
    const short* __restrict__ A, const short* __restrict__ Bw,
    const float* __restrict__ ropeT,
    unsigned short* __restrict__ q_rope, unsigned short* __restrict__ k_ropeT,
    float* __restrict__ kmean)
{
    __shared__ short Atile[64 * 264];       // pitch 264 shorts (pad 8) = 33 KB
    __shared__ float kst[2][32 * 132];      // k-wave transpose stage, 33.8 KB
    const int t = threadIdx.x, lane = t & 63, wv = t >> 6;
    const int m0 = blockIdx.x * 64;         // global token base (b*4096 + tok)
    const int b = m0 >> 12;
    const int tokb = m0 & 4095;
    const int mr = lane & 15, koff = (lane >> 4) * 8, quad = lane >> 4;
    const int n0w = wv * 128;               // output channel base of this wave

    // stage A tile [64 tok][256 k] -> LDS (padded rows)
    {
        const short* src = A + (size_t)m0 * 256;
        #pragma unroll
        for (int i = 0; i < 8; ++i) {
            int flat = i * 2048 + t * 8;
            int row = flat >> 8, col = flat & 255;
            *(s8*)(Atile + row * 264 + col) = *(const s8*)(src + flat);
        }
    }
    __syncthreads();

    f4 acc[4][8];
    #pragma unroll
    for (int a = 0; a < 4; ++a)
        #pragma unroll
        for (int bn = 0; bn < 8; ++bn) { acc[a][bn][0]=0.f; acc[a][bn][1]=0.f; acc[a][bn][2]=0.f; acc[a][bn][3]=0.f; }

    #pragma unroll
    for (int ks = 0; ks < 8; ++ks) {
        const int k0 = ks * 32;
        s8 af[4], bfr[8];
        #pragma unroll
        for (int mt = 0; mt < 4; ++mt)
            af[mt] = *(const s8*)(Atile + (mt * 16 + mr) * 264 + k0 + koff);
        #pragma unroll
        for (int nt = 0; nt < 8; ++nt)
            bfr[nt] = *(const s8*)(Bw + (size_t)(n0w + nt * 16 + mr) * 256 + k0 + koff);
        #pragma unroll
        for (int mt = 0; mt < 4; ++mt)
            #pragma unroll
            for (int nt = 0; nt < 8; ++nt)
                acc[mt][nt] = __builtin_amdgcn_mfma_f32_16x16x32_bf16(af[mt], bfr[nt], acc[mt][nt], 0, 0, 0);
    }

    if (wv < 2) {
        // ---- q half: RoPE in registers, direct b16 stores ----
        #pragma unroll
        for (int mt = 0; mt < 4; ++mt) {
            #pragma unroll
            for (int r = 0; r < 4; ++r) {
                int tok = m0 + mt * 16 + quad * 4 + r;
                int w = tok & 63;
                unsigned short* orow = q_rope + (size_t)tok * 256;
                #pragma unroll
                for (int nt = 0; nt < 8; ++nt) {
                    int ch = n0w + nt * 16 + mr;
                    float v = acc[mt][nt][r];
                    v = v > 0.f ? v + 1.f : __expf(v);
                    float pv = __shfl_xor(v, 1);
                    int jj = ch >> 1;
                    f2 cs = *(const f2*)(ropeT + (w * 128 + jj) * 2);
                    float o = (ch & 1) ? cs[1] * pv + cs[0] * v : cs[0] * v - cs[1] * pv;
                    orow[ch] = f2bf(o);
                }
            }
        }
    } else {
        // ---- k half: per-wave LDS transpose + RoPE + kmean ----
        float* sw = kst[wv - 2];
        float ksum[2] = {0.f, 0.f};
        for (int half = 0; half < 2; ++half) {
            #pragma unroll
            for (int mt2 = 0; mt2 < 2; ++mt2) {
                int mt = half * 2 + mt2;
                #pragma unroll
                for (int nt = 0; nt < 8; ++nt)
                    #pragma unroll
                    for (int r = 0; r < 4; ++r) {
                        float v = acc[mt][nt][r];
                        v = v > 0.f ? v + 1.f : __expf(v);
                        sw[(mt2 * 16 + quad * 4 + r) * 132 + nt * 16 + mr] = v;
                    }
            }
            // same-wave RAW through LDS: ordered by waitcnt, no barrier needed
            #pragma unroll
            for (int cc = 0; cc < 2; ++cc) {
                int col = cc * 64 + lane;
                int kidx = (wv - 2) * 128 + col;      // 0..255
                int jj = kidx >> 1;
                unsigned short obuf[32];
                float ks = 0.f;
                #pragma unroll
                for (int i = 0; i < 32; ++i) {
                    float v = sw[i * 132 + col];
                    ks += v;
                    float pv = __shfl_xor(v, 1);
                    int w = (tokb + half * 32 + i) & 63;
                    f2 cs = *(const f2*)(ropeT + (w * 128 + jj) * 2);
                    obuf[i] = f2bf((kidx & 1) ? cs[1] * pv + cs[0] * v : cs[0] * v - cs[1] * pv);
                }
                unsigned short* dst = k_ropeT + (size_t)(b * 256 + kidx) * 4096 + tokb + half * 32;
                #pragma unroll
                for (int u = 0; u < 4; ++u)
                    *(us8*)(dst + u * 8) = *(const us8*)(obuf + u * 8);
                ksum[cc] += ks;
            }
        }
        atomicAdd(&kmean[b * 256 + (wv - 2) * 128 + lane], ksum[0] * (1.0f / 4096.0f));
        atomicAdd(&kmean[b * 256 + (wv - 2) * 128 + 64 + lane], ksum[1] * (1.0f / 4096.0f));
    }
}

// ---------------------------------------------------------------------------
// K5: kv[d,e] = (1/n) sum_n k_rope[n,d] v[n,e] via bf16 MFMA. Split-K = 4.
// grid (4 splits, 4 h, 16 b), block 256
// ---------------------------------------------------------------------------
__global__ __launch_bounds__(256) void k5_kv(
    const unsigned short* __restrict__ kT, const unsigned short* __restrict__ vT,
    float* __restrict__ kv)
{
    __shared__ float red[4 * 4096];
    const int t = threadIdx.x, lane = t & 63, wv = t >> 6;
    const int mr = lane & 15, koff = (lane >> 4) * 8, quad = lane >> 4;
    const int s = blockIdx.x, h = blockIdx.y, b = blockIdx.z;

    f4 acc[4][4];
    #pragma unroll
    for (int a = 0; a < 4; ++a)
        #pragma unroll
        for (int bn = 0; bn < 4; ++bn) { acc[a][bn][0]=0.f; acc[a][bn][1]=0.f; acc[a][bn][2]=0.f; acc[a][bn][3]=0.f; }

    #pragma unroll 1
    for (int it = 0; it < 4; ++it) {
        const int tok0 = s * 1024 + it * 256 + wv * 64;
        const unsigned short* Ab = kT + (size_t)(b * 256 + h * 64) * 4096 + tok0;
        const unsigned short* Bb = vT + (size_t)(b * 256 + h * 64) * 4096 + tok0;
        #pragma unroll
        for (int ks = 0; ks < 2; ++ks) {
            s8 af[4], bfr[4];
            #pragma unroll
            for (int mt = 0; mt < 4; ++mt)
                af[mt] = *(const s8*)(Ab + (size_t)(mt * 16 + mr) * 4096 + ks * 32 + koff);
            #pragma unroll
            for (int nt = 0; nt < 4; ++nt)
                bfr[nt] = *(const s8*)(Bb + (size_t)(nt * 16 + mr) * 4096 + ks * 32 + koff);
            #pragma unroll
            for (int mt = 0; mt < 4; ++mt)
                #pragma unroll
                for (int nt = 0; nt < 4; ++nt)
                    acc[mt][nt] = __builtin_amdgcn_mfma_f32_16x16x32_bf16(af[mt], bfr[nt], acc[mt][nt], 0, 0, 0);
        }
    }

    float* rw = red + wv * 4096;
    #pragma unroll
    for (int mt = 0; mt < 4; ++mt)
        #pragma unroll
        for (int nt = 0; nt < 4; ++nt)
            #pragma unroll
            for (int r = 0; r < 4; ++r)
                rw[(mt * 16 + quad * 4 + r) * 64 + nt * 16 + mr] = acc[mt][nt][r];
    __syncthreads();

    float* kvp = kv + (size_t)(b * 4 + h) * 4096;
    for (int i = 0; i < 16; ++i) {
        int idx = i * 256 + t;
        float s4 = red[idx] + red[4096 + idx] + red[8192 + idx] + red[12288 + idx];
        atomicAdd(&kvp[idx], s4 * (1.0f / 4096.0f));
    }
}

// ---------------------------------------------------------------------------
// K6: attn = (q_rope @ kv) * z via bf16 MFMA; z via rotated-kmean (table);
//     epilogue LDS transpose + FUSED LePE 3x3 (+bias) -> single write of
//     d_out [b,c,n]. [R10-verified version: direct global vT gather — the
//     R11 LDS-staging variant cost occupancy (77.8 KB LDS) and regressed.]
// grid (16 ntiles, 4 h, 16 b), block 256
// ---------------------------------------------------------------------------
__global__ __launch_bounds__(256) void k6_attn(
    const unsigned short* __restrict__ q_rope, const float* __restrict__ kmean,
    const float* __restrict__ kv, const float* __restrict__ ropeT,
    const unsigned short* __restrict__ vT, const float* __restrict__ lw,
    const float* __restrict__ lb, float* __restrict__ out)
{
    __shared__ unsigned short kvB[64 * 64];
    __shared__ float zl[256];
    __shared__ float kml[64];
    __shared__ float trans[4][32 * 65];
    const int t = threadIdx.x, lane = t & 63, wv = t >> 6;
    const int mr = lane & 15, koff = (lane >> 4) * 8, quad = lane >> 4;
    const int ntb = blockIdx.x, h = blockIdx.y, b = blockIdx.z;
    const int n0 = ntb * 256;

    {
        const float* kvp = kv + (size_t)(b * 4 + h) * 4096;
        int e = t >> 2, dseg = (t & 3) * 16;
        unsigned short tmp[16];
        #pragma unroll
        for (int i = 0; i < 16; ++i) tmp[i] = f2bf(kvp[(dseg + i) * 64 + e]);
        *(us8*)&kvB[e * 64 + dseg]     = *(const us8*)tmp;
        *(us8*)&kvB[e * 64 + dseg + 8] = *(const us8*)(tmp + 8);
    }
    if (t < 64) kml[t] = kmean[b * 256 + h * 64 + t];
    __syncthreads();

    {
        const unsigned short* qp = q_rope + (size_t)(b * 4096 + n0 + t) * 256 + h * 64;
        float q[64];
        #pragma unroll
        for (int u = 0; u < 8; ++u) {
            us8 v = *(const us8*)(qp + u * 8);
            #pragma unroll
            for (int j = 0; j < 8; ++j) q[u * 8 + j] = bf2f(v[j]);
        }
        int w = (n0 + t) & 63;
        float den = 0.f;
        #pragma unroll
        for (int j = 0; j < 32; ++j) {
            f2 cs = *(const f2*)(ropeT + (w * 128 + h * 32 + j) * 2);
            float kmx = kml[2 * j], kmy = kml[2 * j + 1];
            den += q[2 * j] * (cs[0] * kmx - cs[1] * kmy) + q[2 * j + 1] * (cs[1] * kmx + cs[0] * kmy);
        }
        zl[t] = 1.0f / (den + 1e-6f);
    }
    __syncthreads();

    s8 bfr[4][2];
    #pragma unroll
    for (int nt = 0; nt < 4; ++nt)
        #pragma unroll
        for (int ks = 0; ks < 2; ++ks)
            bfr[nt][ks] = *(const s8*)&kvB[(nt * 16 + mr) * 64 + ks * 32 + koff];

    const unsigned short* Ab = q_rope + (size_t)(b * 4096 + n0 + wv * 64) * 256 + h * 64;
    f4 acc[4][4];
    #pragma unroll
    for (int a = 0; a < 4; ++a)
        #pragma unroll
        for (int bn = 0; bn < 4; ++bn) { acc[a][bn][0]=0.f; acc[a][bn][1]=0.f; acc[a][bn][2]=0.f; acc[a][bn][3]=0.f; }

    #pragma unroll
    for (int ks = 0; ks < 2; ++ks) {
        s8 af[4];
        #pragma unroll
        for (int mt = 0; mt < 4; ++mt)
            af[mt] = *(const s8*)(Ab + (size_t)(mt * 16 + mr) * 256 + ks * 32 + koff);
        #pragma unroll
        for (int mt = 0; mt < 4; ++mt)
            #pragma unroll
            for (int nt = 0; nt < 4; ++nt)
                acc[mt][nt] = __builtin_amdgcn_mfma_f32_16x16x32_bf16(af[mt], bfr[nt][ks], acc[mt][nt], 0, 0, 0);
    }

    // LePE weights for this thread's channel c = h*64 + lane
    const int c = h * 64 + lane;
    f4 lwa = *(const f4*)(lw + c * 9);
    f4 lwb = *(const f4*)(lw + c * 9 + 4);
    float lw8 = lw[c * 9 + 8];
    float bias = lb[c];
    const unsigned short* vch = vT + (size_t)(b * 256 + c) * 4096;

    float* sw = trans[wv];
    #pragma unroll
    for (int half = 0; half < 2; ++half) {
        #pragma unroll
        for (int mt2 = 0; mt2 < 2; ++mt2) {
            #pragma unroll
            for (int r = 0; r < 4; ++r) {
                int row_rel = mt2 * 16 + quad * 4 + r;
                float z = zl[wv * 64 + half * 32 + row_rel];
                #pragma unroll
                for (int nt = 0; nt < 4; ++nt)
                    sw[row_rel * 65 + nt * 16 + mr] = acc[half * 2 + mt2][nt][r] * z;
            }
        }
        __syncthreads();
        float tmp[32];
        #pragma unroll
        for (int i = 0; i < 32; ++i) tmp[i] = sw[i * 65 + lane] + bias;

        // --- fused LePE: output row r = 4*ntb + wv, cols CST..CST+31 ---
        const int rimg = 4 * ntb + wv;          // wave-uniform
        const int CST = half * 32;              // compile-time (half unrolled)
        #pragma unroll
        for (int dy = -1; dy <= 1; ++dy) {
            int rr = rimg + dy;
            if ((unsigned)rr < 64u) {           // wave-uniform branch
                const unsigned short* vp = vch + rr * 64 + CST - 8;
                // f[i] = v[col = CST-1+i], i = 0..33  (buf idx i+7)
                float f[34];
                {
                    unsigned short e0 = vp[7];
                    us8 v1 = *(const us8*)(vp + 8);
                    us8 v2 = *(const us8*)(vp + 16);
                    us8 v3 = *(const us8*)(vp + 24);
                    us8 v4 = *(const us8*)(vp + 32);
                    unsigned short e5 = vp[40];
                    f[0] = bf2f(e0);
                    #pragma unroll
                    for (int j = 0; j < 8; ++j) {
                        f[1 + j]  = bf2f(v1[j]);
                        f[9 + j]  = bf2f(v2[j]);
                        f[17 + j] = bf2f(v3[j]);
                        f[25 + j] = bf2f(v4[j]);
                    }
                    f[33] = bf2f(e5);
                }
                if (CST == 0)  f[0]  = 0.f;     // col -1 pad
                if (CST == 32) f[33] = 0.f;     // col 64 pad
                float w0, w1, w2;
                if (dy == -1)      { w0 = lwa[0]; w1 = lwa[1]; w2 = lwa[2]; }
                else if (dy == 0)  { w0 = lwa[3]; w1 = lwb[0]; w2 = lwb[1]; }
                else               { w0 = lwb[2]; w1 = lwb[3]; w2 = lw8;    }
                #pragma unroll
                for (int j = 0; j < 32; ++j) {
                    float o = tmp[j];
                    o = fmaf(w0, f[j], o);
                    o = fmaf(w1, f[j + 1], o);
                    o = fmaf(w2, f[j + 2], o);
                    tmp[j] = o;
                }
            }
        }

        float* orow = out + (size_t)(b * 256 + c) * 4096 + n0 + wv * 64 + half * 32;
        #pragma unroll
        for (int u = 0; u < 8; ++u)
            *(f4*)(orow + u * 4) = *(const f4*)(tmp + u * 4);
        __syncthreads();
    }
}

// ---------------------------------------------------------------------------
extern "C" void kernel_launch(void* const* d_in, const int* in_sizes, int n_in,
                              void* d_out, int out_size, void* d_ws, size_t ws_size,
                              hipStream_t stream)
{
    const float* x   = (const float*)d_in[0];
    const float* w3  = (const float*)d_in[1];  const float* b3 = (const float*)d_in[2];
    const float* w5  = (const float*)d_in[3];  const float* b5 = (const float*)d_in[4];
    const float* w7  = (const float*)d_in[5];  const float* b7 = (const float*)d_in[6];
    const float* w9  = (const float*)d_in[7];  const float* b9 = (const float*)d_in[8];
    const float* gnw = (const float*)d_in[9];  const float* gnb = (const float*)d_in[10];
    const float* fw  = (const float*)d_in[11];
    const float* qkw = (const float*)d_in[12];
    const float* lw  = (const float*)d_in[13]; const float* lb = (const float*)d_in[14];

    char* ws = (char*)d_ws;
    // layout (bytes):
    //   [0, 128MiB)     y bf16 [4][B][C][N]  -- ALIASED later by q_rope (0..32M)
    //                   and k_ropeT (32M..64M); y dead after k2.
    //   [128M, 160M)    xs bf16 [B][N][C]
    //   [160M, 192M)    vT bf16 [B][C][N]
    //   [192M, +256K)   qk_w bf16
    //   then stats (2KB) | kmean (16KB) | kv fp32 (1MB)  -- one memset
    //   then ropeT fp32 64KB (fully overwritten by k0, no memset)
    unsigned short* y      = (unsigned short*)(ws + 0);
    unsigned short* q_rope = (unsigned short*)(ws + 0);
    unsigned short* kT     = (unsigned short*)(ws + 33554432ull);
    unsigned short* xs     = (unsigned short*)(ws + 134217728ull);
    unsigned short* vT     = (unsigned short*)(ws + 167772160ull);
    unsigned short* wb     = (unsigned short*)(ws + 201326592ull);
    float*          stats  = (float*)(ws + 201588736ull);
    float*          kmean  = (float*)(ws + 201590784ull);
    float*          kv     = (float*)(ws + 201607168ull);
    float*          ropeT  = (float*)(ws + 202655744ull);

    (void)hipMemsetAsync(stats, 0, 2048 + 16384 + 1048576, stream);

    k0_setup<<<dim3(512), 256, 0, stream>>>(ropeT, qkw, wb);
    k1_conv_stats<<<dim3(256, 16), 256, 0, stream>>>(x, w3, b3, w5, b5, w7, b7, w9, b9, y, stats);
    k2_fuse<<<dim3(64, 4, 16), 256, 0, stream>>>(y, stats, gnw, gnb, fw, xs, vT);
    k3_gemm<<<dim3(1024), 256, 0, stream>>>((const short*)xs, (const short*)wb, ropeT, q_rope, kT, kmean);
    k5_kv<<<dim3(4, 4, 16), 256, 0, stream>>>(kT, vT, kv);
    k6_attn<<<dim3(16, 4, 16), 256, 0, stream>>>(q_rope, kmean, kv, ropeT, vT, lw, lb, (float*)d_out);
}

// Round 14
// 383.802 us; speedup vs baseline: 1.1332x; 1.0488x over previous
//
#include <hip/hip_runtime.h>
#include <hip/hip_bf16.h>

#define B_ 16
#define C_ 256
#define N_ 4096

// log2(10000)/128
#define THK (13.287712379549449f / 128.f)

typedef float f4 __attribute__((ext_vector_type(4)));
typedef float f2 __attribute__((ext_vector_type(2)));
typedef short s8 __attribute__((ext_vector_type(8)));
typedef unsigned short us8 __attribute__((ext_vector_type(8)));
typedef unsigned int u4 __attribute__((ext_vector_type(4)));
typedef __fp16 hv2 __attribute__((ext_vector_type(2)));

__device__ __forceinline__ float bf2f(unsigned short u) {
    unsigned int ui = ((unsigned int)u) << 16;
    return __uint_as_float(ui);
}
__device__ __forceinline__ unsigned short f2bf(float f) {
    unsigned int ui = __float_as_uint(f);
    ui += 0x7fffu + ((ui >> 16) & 1u);
    return (unsigned short)(ui >> 16);
}

// packed f16 helpers (builtins use __fp16 vectors, NOT _Float16)
__device__ __forceinline__ unsigned int pk2h(float a, float b) {
#if __has_builtin(__builtin_amdgcn_cvt_pkrtz)
    union { hv2 h; unsigned int u; } x;
    x.h = __builtin_amdgcn_cvt_pkrtz(a, b);
    return x.u;
#else
    union { __fp16 h[2]; unsigned int u; } x;
    x.h[0] = (__fp16)a; x.h[1] = (__fp16)b; return x.u;
#endif
}
__device__ __forceinline__ float DOT2(unsigned int w, unsigned int xp, float c) {
    union { unsigned int u; hv2 h; } a, b; a.u = w; b.u = xp;
#if __has_builtin(__builtin_amdgcn_fdot2)
    return __builtin_amdgcn_fdot2(a.h, b.h, c, false);
#else
    return c + (float)a.h[0] * (float)b.h[0] + (float)a.h[1] * (float)b.h[1];
#endif
}

// ---------------------------------------------------------------------------
// K0: setup — qkw f32->bf16 cvt (all 131072 threads), RoPE table (first 8192),
// and zeroing of the stats|kmean|kv region (266752 contiguous floats).
// grid (512), block 256
// ---------------------------------------------------------------------------
__global__ __launch_bounds__(256) void k0_setup(float* __restrict__ ropeT,
                                                const float* __restrict__ w,
                                                unsigned short* __restrict__ o,
                                                float* __restrict__ zb)
{
    int i = blockIdx.x * 256 + threadIdx.x;     // 0..131071
    o[i] = f2bf(w[i]);
    zb[i] = 0.f;
    zb[i + 131072] = 0.f;                       // 262144 covered
    if (i < 4608) zb[i + 262144] = 0.f;         // 266752 total
    if (i < 8192) {
        int wr = i >> 7, jj = i & 127;
        float theta = exp2f(-(float)jj * THK);
        float sv, cv; sincosf((float)wr * theta, &sv, &cv);
        ropeT[i * 2] = cv; ropeT[i * 2 + 1] = sv;
    }
}

// ---------------------------------------------------------------------------
// K1: 4 depthwise convs (k=3,5,7,9) via v_dot2_f32_f16 (best measured variant:
// 117us, VGPR 56). One block = one (b,c) 64x64 image; thread = 1 row x 16 cols.
// grid (256 c, 16 b), block 256. Tile: 72 rows x 88-pitch f16 (12.4 KB).
// ---------------------------------------------------------------------------
__global__ __launch_bounds__(256, 4) void k1_conv_stats(
    const float* __restrict__ x,
    const float* __restrict__ cw3, const float* __restrict__ cb3,
    const float* __restrict__ cw5, const float* __restrict__ cb5,
    const float* __restrict__ cw7, const float* __restrict__ cb7,
    const float* __restrict__ cw9, const float* __restrict__ cb9,
    unsigned short* __restrict__ y,   // [4][B][C][N] bf16
    float* __restrict__ stats)        // [4][B][4][2]
{
    __shared__ __align__(16) unsigned short tile[72 * 88];
    __shared__ __align__(16) unsigned int wtab[9][16];
    __shared__ float red[4][8];
    const int t = threadIdx.x;
    const int c  = blockIdx.x;
    const int b  = blockIdx.y;

    const float* xc = x + (size_t)(b * C_ + c) * N_;

    if (t < 144) {
        int r = t >> 4, slot = t & 15;
        float w0 = 0.f, w1 = 0.f;
        if (slot < 5) {
            int dx = slot * 2;
            w0 = cw9[c * 81 + r * 9 + dx];
            if (dx + 1 < 9) w1 = cw9[c * 81 + r * 9 + dx + 1];
        } else if (slot < 9) {
            int r7 = r - 1;
            if ((unsigned)r7 < 7u) {
                int dx = (slot - 5) * 2;
                w0 = cw7[c * 49 + r7 * 7 + dx];
                if (dx + 1 < 7) w1 = cw7[c * 49 + r7 * 7 + dx + 1];
            }
        } else if (slot < 12) {
            int r5 = r - 2;
            if ((unsigned)r5 < 5u) {
                int dx = (slot - 9) * 2;
                w0 = cw5[c * 25 + r5 * 5 + dx];
                if (dx + 1 < 5) w1 = cw5[c * 25 + r5 * 5 + dx + 1];
            }
        } else if (slot < 14) {
            int r3 = r - 3;
            if ((unsigned)r3 < 3u) {
                int dx = (slot - 12) * 2;
                w0 = cw3[c * 9 + r3 * 3 + dx];
                if (dx + 1 < 3) w1 = cw3[c * 9 + r3 * 3 + dx + 1];
            }
        }
        wtab[r][slot] = pk2h(w0, w1);
    }

    #pragma unroll 1
    for (int i = 0; i < 13; ++i) {
        int flat = i * 256 + t;              // pair index, 72*44 = 3168
        if (flat < 72 * 44) {
            int r = flat / 44, cp = flat % 44;
            int h = r - 4;
            int w0i = cp * 2 - 4, w1i = w0i + 1;
            float v0 = 0.f, v1 = 0.f;
            if ((unsigned)h < 64u) {
                const float* row = xc + h * 64;
                if ((unsigned)w0i < 64u) v0 = row[w0i];
                if ((unsigned)w1i < 64u) v1 = row[w1i];
            }
            *(unsigned int*)&tile[r * 88 + cp * 2] = pk2h(v0, v1);
        }
    }
    __syncthreads();

    const int w16 = (t & 3) * 16;   // column base: 0/16/32/48
    const int hr  = t >> 2;         // output row: 0..63
    float a3[16], a5[16], a7[16], a9[16];
    #pragma unroll
    for (int j = 0; j < 16; ++j) { a3[j]=0.f; a5[j]=0.f; a7[j]=0.f; a9[j]=0.f; }

    #pragma unroll 1
    for (int r9 = 0; r9 < 9; ++r9) {
        u4 wv0 = *(const u4*)&wtab[r9][0];
        u4 wv1 = *(const u4*)&wtab[r9][4];
        u4 wv2 = *(const u4*)&wtab[r9][8];
        u4 wv3 = *(const u4*)&wtab[r9][12];
        unsigned int wt[16] = { wv0[0],wv0[1],wv0[2],wv0[3],
                                wv1[0],wv1[1],wv1[2],wv1[3],
                                wv2[0],wv2[1],wv2[2],wv2[3],
                                wv3[0],wv3[1],wv3[2],wv3[3] };

        const unsigned short* xr = &tile[(hr + r9) * 88 + w16];
        u4 e0 = *(const u4*)(xr);
        u4 e1 = *(const u4*)(xr + 8);
        u4 e2 = *(const u4*)(xr + 16);
        unsigned int xe12 = *(const unsigned int*)(xr + 24);
        unsigned int xe[13] = { e0[0],e0[1],e0[2],e0[3],
                                e1[0],e1[1],e1[2],e1[3],
                                e2[0],e2[1],e2[2],e2[3], xe12 };
        unsigned int xo[12];
        #pragma unroll
        for (int k2 = 0; k2 < 12; ++k2)
            xo[k2] = (xe[k2] >> 16) | (xe[k2 + 1] << 16);

        #pragma unroll
        for (int j = 0; j < 16; ++j) {
            const int jh = j >> 1;
            if ((j & 1) == 0) {
                #pragma unroll
                for (int k = 0; k < 5; ++k) a9[j] = DOT2(wt[k], xe[jh + k], a9[j]);
            } else {
                #pragma unroll
                for (int k = 0; k < 5; ++k) a9[j] = DOT2(wt[k], xo[jh + k], a9[j]);
            }
        }
        if ((unsigned)(r9 - 1) < 7u) {
            #pragma unroll
            for (int j = 0; j < 16; ++j) {
                const int jh = j >> 1;
                if ((j & 1) == 0) {
                    #pragma unroll
                    for (int k = 0; k < 4; ++k) a7[j] = DOT2(wt[5 + k], xo[jh + k], a7[j]);
                } else {
                    #pragma unroll
                    for (int k = 0; k < 4; ++k) a7[j] = DOT2(wt[5 + k], xe[jh + 1 + k], a7[j]);
                }
            }
        }
        if ((unsigned)(r9 - 2) < 5u) {
            #pragma unroll
            for (int j = 0; j < 16; ++j) {
                const int jh = j >> 1;
                if ((j & 1) == 0) {
                    #pragma unroll
                    for (int k = 0; k < 3; ++k) a5[j] = DOT2(wt[9 + k], xe[jh + 1 + k], a5[j]);
                } else {
                    #pragma unroll
                    for (int k = 0; k < 3; ++k) a5[j] = DOT2(wt[9 + k], xo[jh + 1 + k], a5[j]);
                }
            }
        }
        if ((unsigned)(r9 - 3) < 3u) {
            #pragma unroll
            for (int j = 0; j < 16; ++j) {
                const int jh = j >> 1;
                if ((j & 1) == 0) {
                    #pragma unroll
                    for (int k = 0; k < 2; ++k) a3[j] = DOT2(wt[12 + k], xo[jh + 1 + k], a3[j]);
                } else {
                    #pragma unroll
                    for (int k = 0; k < 2; ++k) a3[j] = DOT2(wt[12 + k], xe[jh + 2 + k], a3[j]);
                }
            }
        }
    }

    float bb0 = cb3[c], bb1 = cb5[c], bb2 = cb7[c], bb3 = cb9[c];
    float s[4], ss[4];
    const size_t L = (size_t)B_ * C_ * N_;
    size_t ybase = (size_t)(b * C_ + c) * N_ + (size_t)hr * 64 + w16;

    #pragma unroll
    for (int l = 0; l < 4; ++l) {
        float bias = (l == 0) ? bb0 : (l == 1) ? bb1 : (l == 2) ? bb2 : bb3;
        float* ap = (l == 0) ? a3 : (l == 1) ? a5 : (l == 2) ? a7 : a9;
        float s1 = 0.f, s2 = 0.f;
        us8 pk0, pk1;
        #pragma unroll
        for (int j = 0; j < 8; ++j) {
            float v = ap[j] + bias;
            pk0[j] = f2bf(v);
            s1 += v; s2 += v * v;
        }
        #pragma unroll
        for (int j = 8; j < 16; ++j) {
            float v = ap[j] + bias;
            pk1[j - 8] = f2bf(v);
            s1 += v; s2 += v * v;
        }
        *reinterpret_cast<us8*>(y + (size_t)l * L + ybase)     = pk0;
        *reinterpret_cast<us8*>(y + (size_t)l * L + ybase + 8) = pk1;
        s[l] = s1; ss[l] = s2;
    }

    #pragma unroll
    for (int l = 0; l < 4; ++l) {
        float aa = s[l], qq = ss[l];
        for (int off = 1; off < 64; off <<= 1) { aa += __shfl_xor(aa, off); qq += __shfl_xor(qq, off); }
        s[l] = aa; ss[l] = qq;
    }
    const int lane = t & 63, wvi = t >> 6;
    if (lane == 0) {
        #pragma unroll
        for (int l = 0; l < 4; ++l) { red[wvi][l*2] = s[l]; red[wvi][l*2+1] = ss[l]; }
    }
    __syncthreads();
    if (t < 8) {
        float tot = red[0][t] + red[1][t] + red[2][t] + red[3][t];
        int l = t >> 1, which = t & 1, g = c >> 6;
        atomicAdd(&stats[((l * 16 + b) * 4 + g) * 2 + which], tot);
    }
}

// ---------------------------------------------------------------------------
// K23: MERGED k2+k3. Phase A: groupnorm+sigmoid+softmax fusion for this
// block's 64 tokens x all 256 ch, writing vT (coalesced) and staging the
// bf16 values DIRECTLY into the Atile LDS — eliminates the xs intermediate
// (64 MB HBM) and one launch. Values are bitwise-identical to the old xs
// round-trip. Phase B: verified k3 body.
// ALIASING NOTE: q_rope lives in the freed xs slot and kT lives in d_out
// (scratch until k6, which fully overwrites it) — NO alias with y, which
// other blocks' phase A may still be reading while this block runs phase B.
// grid (1024), block 256
// ---------------------------------------------------------------------------
__global__ __launch_bounds__(256, 2) void k23_fuse_gemm(
    const unsigned short* __restrict__ y, const float* __restrict__ stats,
    const float* __restrict__ gnw, const float* __restrict__ gnb,
    const float* __restrict__ fw,
    const short* __restrict__ Bw, const float* __restrict__ ropeT,
    unsigned short* __restrict__ vT,
    unsigned short* __restrict__ q_rope, unsigned short* __restrict__ k_ropeT,
    float* __restrict__ kmean)
{
    __shared__ __align__(16) short Atile[64 * 264];  // pitch 264 (pad 8) = 33 KB
    __shared__ float kst[2][32 * 132];               // k-wave transpose stage
    const int t = threadIdx.x, lane = t & 63, wv = t >> 6;
    const int m0 = blockIdx.x * 64;         // global token base (b*4096 + tok)
    const int b = m0 >> 12;
    const int tokb = m0 & 4095;
    const int mr = lane & 15, koff = (lane >> 4) * 8, quad = lane >> 4;
    const int n0w = wv * 128;               // output channel base of this wave

    // ---- phase A: fusion + staging ----
    {
        float f0 = fw[0], f1 = fw[1], f2v = fw[2], f3 = fw[3];
        float mx = fmaxf(fmaxf(f0, f1), fmaxf(f2v, f3));
        float e0 = __expf(f0 - mx), e1 = __expf(f1 - mx), e2 = __expf(f2v - mx), e3 = __expf(f3 - mx);
        float inv = 1.f / (e0 + e1 + e2 + e3);
        float wts[4] = { e0 * inv, e1 * inv, e2 * inv, e3 * inv };

        float mean[4][4], rstd[4][4];
        const float invN = 1.0f / 262144.0f;
        #pragma unroll
        for (int l = 0; l < 4; ++l)
            #pragma unroll
            for (int g = 0; g < 4; ++g) {
                float s1 = stats[((l * 16 + b) * 4 + g) * 2 + 0];
                float s2 = stats[((l * 16 + b) * 4 + g) * 2 + 1];
                float m = s1 * invN;
                float var = fmaxf(s2 * invN - m * m, 0.f);
                mean[l][g] = m; rstd[l][g] = rsqrtf(var + 1e-5f);
            }

        const size_t L = (size_t)B_ * C_ * N_;
        #pragma unroll 1
        for (int i = 0; i < 8; ++i) {
            int flat = i * 256 + t;          // 0..2047
            int ch = flat >> 3;              // 0..255
            int chunk = flat & 7;            // token chunk (8 tok)
            int g = ch >> 6;
            size_t base = (size_t)(b * C_ + ch) * N_ + tokb + chunk * 8;
            float acc[8];
            #pragma unroll
            for (int j = 0; j < 8; ++j) acc[j] = 0.f;
            #pragma unroll
            for (int l = 0; l < 4; ++l) {
                float sc = rstd[l][g] * gnw[l * 256 + ch];
                float of = gnb[l * 256 + ch] - mean[l][g] * sc;
                float wt = wts[l];
                us8 v = *(const us8*)(y + (size_t)l * L + base);
                #pragma unroll
                for (int j = 0; j < 8; ++j) {
                    float gg = fmaf(bf2f(v[j]), sc, of);
                    acc[j] += wt * (1.0f / (1.0f + __expf(-gg)));
                }
            }
            us8 p;
            #pragma unroll
            for (int j = 0; j < 8; ++j) p[j] = f2bf(acc[j]);
            *(us8*)(vT + base) = p;
            // transposed staging into Atile[tok][ch]
            #pragma unroll
            for (int j = 0; j < 8; ++j)
                Atile[(chunk * 8 + j) * 264 + ch] = (short)p[j];
        }
    }
    __syncthreads();

    // ---- phase B: verified k3 body ----
    f4 acc[4][8];
    #pragma unroll
    for (int a = 0; a < 4; ++a)
        #pragma unroll
        for (int bn = 0; bn < 8; ++bn) { acc[a][bn][0]=0.f; acc[a][bn][1]=0.f; acc[a][bn][2]=0.f; acc[a][bn][3]=0.f; }

    #pragma unroll
    for (int ks = 0; ks < 8; ++ks) {
        const int k0 = ks * 32;
        s8 af[4], bfr[8];
        #pragma unroll
        for (int mt = 0; mt < 4; ++mt)
            af[mt] = *(const s8*)(Atile + (mt * 16 + mr) * 264 + k0 + koff);
        #pragma unroll
        for (int nt = 0; nt < 8; ++nt)
            bfr[nt] = *(const s8*)(Bw + (size_t)(n0w + nt * 16 + mr) * 256 + k0 + koff);
        #pragma unroll
        for (int mt = 0; mt < 4; ++mt)
            #pragma unroll
            for (int nt = 0; nt < 8; ++nt)
                acc[mt][nt] = __builtin_amdgcn_mfma_f32_16x16x32_bf16(af[mt], bfr[nt], acc[mt][nt], 0, 0, 0);
    }

    if (wv < 2) {
        // ---- q half: RoPE in registers, direct b16 stores ----
        #pragma unroll
        for (int mt = 0; mt < 4; ++mt) {
            #pragma unroll
            for (int r = 0; r < 4; ++r) {
                int tok = m0 + mt * 16 + quad * 4 + r;
                int w = tok & 63;
                unsigned short* orow = q_rope + (size_t)tok * 256;
                #pragma unroll
                for (int nt = 0; nt < 8; ++nt) {
                    int ch = n0w + nt * 16 + mr;
                    float v = acc[mt][nt][r];
                    v = v > 0.f ? v + 1.f : __expf(v);
                    float pv = __shfl_xor(v, 1);
                    int jj = ch >> 1;
                    f2 cs = *(const f2*)(ropeT + (w * 128 + jj) * 2);
                    float o = (ch & 1) ? cs[1] * pv + cs[0] * v : cs[0] * v - cs[1] * pv;
                    orow[ch] = f2bf(o);
                }
            }
        }
    } else {
        // ---- k half: per-wave LDS transpose + RoPE + kmean ----
        float* sw = kst[wv - 2];
        float ksum[2] = {0.f, 0.f};
        for (int half = 0; half < 2; ++half) {
            #pragma unroll
            for (int mt2 = 0; mt2 < 2; ++mt2) {
                int mt = half * 2 + mt2;
                #pragma unroll
                for (int nt = 0; nt < 8; ++nt)
                    #pragma unroll
                    for (int r = 0; r < 4; ++r) {
                        float v = acc[mt][nt][r];
                        v = v > 0.f ? v + 1.f : __expf(v);
                        sw[(mt2 * 16 + quad * 4 + r) * 132 + nt * 16 + mr] = v;
                    }
            }
            // same-wave RAW through LDS: ordered by waitcnt, no barrier needed
            #pragma unroll
            for (int cc = 0; cc < 2; ++cc) {
                int col = cc * 64 + lane;
                int kidx = (wv - 2) * 128 + col;      // 0..255
                int jj = kidx >> 1;
                unsigned short obuf[32];
                float ks = 0.f;
                #pragma unroll
                for (int i = 0; i < 32; ++i) {
                    float v = sw[i * 132 + col];
                    ks += v;
                    float pv = __shfl_xor(v, 1);
                    int w = (tokb + half * 32 + i) & 63;
                    f2 cs = *(const f2*)(ropeT + (w * 128 + jj) * 2);
                    obuf[i] = f2bf((kidx & 1) ? cs[1] * pv + cs[0] * v : cs[0] * v - cs[1] * pv);
                }
                unsigned short* dst = k_ropeT + (size_t)(b * 256 + kidx) * 4096 + tokb + half * 32;
                #pragma unroll
                for (int u = 0; u < 4; ++u)
                    *(us8*)(dst + u * 8) = *(const us8*)(obuf + u * 8);
                ksum[cc] += ks;
            }
        }
        atomicAdd(&kmean[b * 256 + (wv - 2) * 128 + lane], ksum[0] * (1.0f / 4096.0f));
        atomicAdd(&kmean[b * 256 + (wv - 2) * 128 + 64 + lane], ksum[1] * (1.0f / 4096.0f));
    }
}

// ---------------------------------------------------------------------------
// K5: kv[d,e] = (1/n) sum_n k_rope[n,d] v[n,e] via bf16 MFMA. Split-K = 4.
// grid (4 splits, 4 h, 16 b), block 256
// ---------------------------------------------------------------------------
__global__ __launch_bounds__(256) void k5_kv(
    const unsigned short* __restrict__ kT, const unsigned short* __restrict__ vT,
    float* __restrict__ kv)
{
    __shared__ float red[4 * 4096];
    const int t = threadIdx.x, lane = t & 63, wv = t >> 6;
    const int mr = lane & 15, koff = (lane >> 4) * 8, quad = lane >> 4;
    const int s = blockIdx.x, h = blockIdx.y, b = blockIdx.z;

    f4 acc[4][4];
    #pragma unroll
    for (int a = 0; a < 4; ++a)
        #pragma unroll
        for (int bn = 0; bn < 4; ++bn) { acc[a][bn][0]=0.f; acc[a][bn][1]=0.f; acc[a][bn][2]=0.f; acc[a][bn][3]=0.f; }

    #pragma unroll 1
    for (int it = 0; it < 4; ++it) {
        const int tok0 = s * 1024 + it * 256 + wv * 64;
        const unsigned short* Ab = kT + (size_t)(b * 256 + h * 64) * 4096 + tok0;
        const unsigned short* Bb = vT + (size_t)(b * 256 + h * 64) * 4096 + tok0;
        #pragma unroll
        for (int ks = 0; ks < 2; ++ks) {
            s8 af[4], bfr[4];
            #pragma unroll
            for (int mt = 0; mt < 4; ++mt)
                af[mt] = *(const s8*)(Ab + (size_t)(mt * 16 + mr) * 4096 + ks * 32 + koff);
            #pragma unroll
            for (int nt = 0; nt < 4; ++nt)
                bfr[nt] = *(const s8*)(Bb + (size_t)(nt * 16 + mr) * 4096 + ks * 32 + koff);
            #pragma unroll
            for (int mt = 0; mt < 4; ++mt)
                #pragma unroll
                for (int nt = 0; nt < 4; ++nt)
                    acc[mt][nt] = __builtin_amdgcn_mfma_f32_16x16x32_bf16(af[mt], bfr[nt], acc[mt][nt], 0, 0, 0);
        }
    }

    float* rw = red + wv * 4096;
    #pragma unroll
    for (int mt = 0; mt < 4; ++mt)
        #pragma unroll
        for (int nt = 0; nt < 4; ++nt)
            #pragma unroll
            for (int r = 0; r < 4; ++r)
                rw[(mt * 16 + quad * 4 + r) * 64 + nt * 16 + mr] = acc[mt][nt][r];
    __syncthreads();

    float* kvp = kv + (size_t)(b * 4 + h) * 4096;
    for (int i = 0; i < 16; ++i) {
        int idx = i * 256 + t;
        float s4 = red[idx] + red[4096 + idx] + red[8192 + idx] + red[12288 + idx];
        atomicAdd(&kvp[idx], s4 * (1.0f / 4096.0f));
    }
}

// ---------------------------------------------------------------------------
// K6: attn = (q_rope @ kv) * z via bf16 MFMA; z via rotated-kmean (table);
//     epilogue LDS transpose + FUSED LePE 3x3 (+bias) -> single write of
//     d_out [b,c,n]. [R10/R12-verified version]
// grid (16 ntiles, 4 h, 16 b), block 256
// ---------------------------------------------------------------------------
__global__ __launch_bounds__(256) void k6_attn(
    const unsigned short* __restrict__ q_rope, const float* __restrict__ kmean,
    const float* __restrict__ kv, const float* __restrict__ ropeT,
    const unsigned short* __restrict__ vT, const float* __restrict__ lw,
    const float* __restrict__ lb, float* __restrict__ out)
{
    __shared__ unsigned short kvB[64 * 64];
    __shared__ float zl[256];
    __shared__ float kml[64];
    __shared__ float trans[4][32 * 65];
    const int t = threadIdx.x, lane = t & 63, wv = t >> 6;
    const int mr = lane & 15, koff = (lane >> 4) * 8, quad = lane >> 4;
    const int ntb = blockIdx.x, h = blockIdx.y, b = blockIdx.z;
    const int n0 = ntb * 256;

    {
        const float* kvp = kv + (size_t)(b * 4 + h) * 4096;
        int e = t >> 2, dseg = (t & 3) * 16;
        unsigned short tmp[16];
        #pragma unroll
        for (int i = 0; i < 16; ++i) tmp[i] = f2bf(kvp[(dseg + i) * 64 + e]);
        *(us8*)&kvB[e * 64 + dseg]     = *(const us8*)tmp;
        *(us8*)&kvB[e * 64 + dseg + 8] = *(const us8*)(tmp + 8);
    }
    if (t < 64) kml[t] = kmean[b * 256 + h * 64 + t];
    __syncthreads();

    {
        const unsigned short* qp = q_rope + (size_t)(b * 4096 + n0 + t) * 256 + h * 64;
        float q[64];
        #pragma unroll
        for (int u = 0; u < 8; ++u) {
            us8 v = *(const us8*)(qp + u * 8);
            #pragma unroll
            for (int j = 0; j < 8; ++j) q[u * 8 + j] = bf2f(v[j]);
        }
        int w = (n0 + t) & 63;
        float den = 0.f;
        #pragma unroll
        for (int j = 0; j < 32; ++j) {
            f2 cs = *(const f2*)(ropeT + (w * 128 + h * 32 + j) * 2);
            float kmx = kml[2 * j], kmy = kml[2 * j + 1];
            den += q[2 * j] * (cs[0] * kmx - cs[1] * kmy) + q[2 * j + 1] * (cs[1] * kmx + cs[0] * kmy);
        }
        zl[t] = 1.0f / (den + 1e-6f);
    }
    __syncthreads();

    s8 bfr[4][2];
    #pragma unroll
    for (int nt = 0; nt < 4; ++nt)
        #pragma unroll
        for (int ks = 0; ks < 2; ++ks)
            bfr[nt][ks] = *(const s8*)&kvB[(nt * 16 + mr) * 64 + ks * 32 + koff];

    const unsigned short* Ab = q_rope + (size_t)(b * 4096 + n0 + wv * 64) * 256 + h * 64;
    f4 acc[4][4];
    #pragma unroll
    for (int a = 0; a < 4; ++a)
        #pragma unroll
        for (int bn = 0; bn < 4; ++bn) { acc[a][bn][0]=0.f; acc[a][bn][1]=0.f; acc[a][bn][2]=0.f; acc[a][bn][3]=0.f; }

    #pragma unroll
    for (int ks = 0; ks < 2; ++ks) {
        s8 af[4];
        #pragma unroll
        for (int mt = 0; mt < 4; ++mt)
            af[mt] = *(const s8*)(Ab + (size_t)(mt * 16 + mr) * 256 + ks * 32 + koff);
        #pragma unroll
        for (int mt = 0; mt < 4; ++mt)
            #pragma unroll
            for (int nt = 0; nt < 4; ++nt)
                acc[mt][nt] = __builtin_amdgcn_mfma_f32_16x16x32_bf16(af[mt], bfr[nt][ks], acc[mt][nt], 0, 0, 0);
    }

    // LePE weights for this thread's channel c = h*64 + lane
    const int c = h * 64 + lane;
    f4 lwa = *(const f4*)(lw + c * 9);
    f4 lwb = *(const f4*)(lw + c * 9 + 4);
    float lw8 = lw[c * 9 + 8];
    float bias = lb[c];
    const unsigned short* vch = vT + (size_t)(b * 256 + c) * 4096;

    float* sw = trans[wv];
    #pragma unroll
    for (int half = 0; half < 2; ++half) {
        #pragma unroll
        for (int mt2 = 0; mt2 < 2; ++mt2) {
            #pragma unroll
            for (int r = 0; r < 4; ++r) {
                int row_rel = mt2 * 16 + quad * 4 + r;
                float z = zl[wv * 64 + half * 32 + row_rel];
                #pragma unroll
                for (int nt = 0; nt < 4; ++nt)
                    sw[row_rel * 65 + nt * 16 + mr] = acc[half * 2 + mt2][nt][r] * z;
            }
        }
        __syncthreads();
        float tmp[32];
        #pragma unroll
        for (int i = 0; i < 32; ++i) tmp[i] = sw[i * 65 + lane] + bias;

        // --- fused LePE: output row r = 4*ntb + wv, cols CST..CST+31 ---
        const int rimg = 4 * ntb + wv;          // wave-uniform
        const int CST = half * 32;              // compile-time (half unrolled)
        #pragma unroll
        for (int dy = -1; dy <= 1; ++dy) {
            int rr = rimg + dy;
            if ((unsigned)rr < 64u) {           // wave-uniform branch
                const unsigned short* vp = vch + rr * 64 + CST - 8;
                // f[i] = v[col = CST-1+i], i = 0..33  (buf idx i+7)
                float f[34];
                {
                    unsigned short e0 = vp[7];
                    us8 v1 = *(const us8*)(vp + 8);
                    us8 v2 = *(const us8*)(vp + 16);
                    us8 v3 = *(const us8*)(vp + 24);
                    us8 v4 = *(const us8*)(vp + 32);
                    unsigned short e5 = vp[40];
                    f[0] = bf2f(e0);
                    #pragma unroll
                    for (int j = 0; j < 8; ++j) {
                        f[1 + j]  = bf2f(v1[j]);
                        f[9 + j]  = bf2f(v2[j]);
                        f[17 + j] = bf2f(v3[j]);
                        f[25 + j] = bf2f(v4[j]);
                    }
                    f[33] = bf2f(e5);
                }
                if (CST == 0)  f[0]  = 0.f;     // col -1 pad
                if (CST == 32) f[33] = 0.f;     // col 64 pad
                float w0, w1, w2;
                if (dy == -1)      { w0 = lwa[0]; w1 = lwa[1]; w2 = lwa[2]; }
                else if (dy == 0)  { w0 = lwa[3]; w1 = lwb[0]; w2 = lwb[1]; }
                else               { w0 = lwb[2]; w1 = lwb[3]; w2 = lw8;    }
                #pragma unroll
                for (int j = 0; j < 32; ++j) {
                    float o = tmp[j];
                    o = fmaf(w0, f[j], o);
                    o = fmaf(w1, f[j + 1], o);
                    o = fmaf(w2, f[j + 2], o);
                    tmp[j] = o;
                }
            }
        }

        float* orow = out + (size_t)(b * 256 + c) * 4096 + n0 + wv * 64 + half * 32;
        #pragma unroll
        for (int u = 0; u < 8; ++u)
            *(f4*)(orow + u * 4) = *(const f4*)(tmp + u * 4);
        __syncthreads();
    }
}

// ---------------------------------------------------------------------------
extern "C" void kernel_launch(void* const* d_in, const int* in_sizes, int n_in,
                              void* d_out, int out_size, void* d_ws, size_t ws_size,
                              hipStream_t stream)
{
    const float* x   = (const float*)d_in[0];
    const float* w3  = (const float*)d_in[1];  const float* b3 = (const float*)d_in[2];
    const float* w5  = (const float*)d_in[3];  const float* b5 = (const float*)d_in[4];
    const float* w7  = (const float*)d_in[5];  const float* b7 = (const float*)d_in[6];
    const float* w9  = (const float*)d_in[7];  const float* b9 = (const float*)d_in[8];
    const float* gnw = (const float*)d_in[9];  const float* gnb = (const float*)d_in[10];
    const float* fw  = (const float*)d_in[11];
    const float* qkw = (const float*)d_in[12];
    const float* lw  = (const float*)d_in[13]; const float* lb = (const float*)d_in[14];

    char* ws = (char*)d_ws;
    // layout (bytes):
    //   [0, 128MiB)     y bf16 [4][B][C][N]  -- live until k23 completes;
    //                   NOT aliased by anything (race-free merge).
    //   [128M, 160M)    q_rope bf16 [B*N][C]  (freed xs slot)
    //   [160M, 192M)    vT bf16 [B][C][N]
    //   [192M, +256K)   qk_w bf16
    //   then stats (2KB) | kmean (16KB) | kv fp32 (1MB) -- zeroed by k0_setup
    //   then ropeT fp32 64KB (fully overwritten by k0_setup)
    //   kT bf16 [B][C][N] (32MB) lives in d_out (scratch until k6, which
    //   fully overwrites every element of out).
    unsigned short* y      = (unsigned short*)(ws + 0);
    unsigned short* q_rope = (unsigned short*)(ws + 134217728ull);
    unsigned short* vT     = (unsigned short*)(ws + 167772160ull);
    unsigned short* wb     = (unsigned short*)(ws + 201326592ull);
    float*          stats  = (float*)(ws + 201588736ull);
    float*          kmean  = (float*)(ws + 201590784ull);
    float*          kv     = (float*)(ws + 201607168ull);
    float*          ropeT  = (float*)(ws + 202655744ull);
    unsigned short* kT     = (unsigned short*)d_out;

    k0_setup<<<dim3(512), 256, 0, stream>>>(ropeT, qkw, wb, stats);
    k1_conv_stats<<<dim3(256, 16), 256, 0, stream>>>(x, w3, b3, w5, b5, w7, b7, w9, b9, y, stats);
    k23_fuse_gemm<<<dim3(1024), 256, 0, stream>>>(y, stats, gnw, gnb, fw,
                                                  (const short*)wb, ropeT, vT, q_rope, kT, kmean);
    k5_kv<<<dim3(4, 4, 16), 256, 0, stream>>>(kT, vT, kv);
    k6_attn<<<dim3(16, 4, 16), 256, 0, stream>>>(q_rope, kmean, kv, ropeT, vT, lw, lb, (float*)d_out);
}